// Round 2
// baseline (3864.380 us; speedup 1.0000x reference)
//
#include <hip/hip_runtime.h>
#include <math.h>

typedef float floatx4 __attribute__((ext_vector_type(4)));
typedef short short8 __attribute__((ext_vector_type(8)));
typedef __bf16 bf16x8 __attribute__((ext_vector_type(8)));

#define BKP 40  // padded LDS row stride in ushorts (80B = 5*16B, 16B-aligned)

__device__ inline unsigned short to_bf16(float f) {
  union { float f; unsigned u; } v; v.f = f;
  unsigned u = v.u;
  u += 0x7FFFu + ((u >> 16) & 1u);
  return (unsigned short)(u >> 16);
}

struct GemmArgs {
  const float* A; int lda; long sA1, sA2;
  const void* B; int ldb; long sB1, sB2;
  float* C; int ldc; long sC1, sC2;
  int M, N, K;
  float alpha;
  const float* bias;
  const float* res; int ldres; long sR1, sR2;
  int bmode;  // 0: B bf16 [n][k]; 1: B fp32 [n][k]; 2: B fp32 [k][n]
  int act;    // 0 none, 1 exact gelu
  int bdiv;   // z -> (z/bdiv, z%bdiv)
  int smode;  // 1: scatter-add C[row][col+row-511] += v (rel-pos shift)
};

__global__ __launch_bounds__(256) void gemm_k(GemmArgs g) {
  int z = blockIdx.z;
  int zi = z / g.bdiv, zj = z % g.bdiv;
  const float* A = g.A + (long)zi * g.sA1 + (long)zj * g.sA2;
  float* C = g.C + (long)zi * g.sC1 + (long)zj * g.sC2;
  long boff = (long)zi * g.sB1 + (long)zj * g.sB2;
  const unsigned short* Bt = (const unsigned short*)g.B + boff;
  const float* Bf = (const float*)g.B + boff;
  const float* res = g.res ? g.res + (long)zi * g.sR1 + (long)zj * g.sR2 : nullptr;

  int m0 = blockIdx.y * 64, n0 = blockIdx.x * 64;
  __shared__ unsigned short As[64][BKP];
  __shared__ unsigned short Bs[64][BKP];

  int tid = threadIdx.x;
  int wave = tid >> 6, lane = tid & 63;
  int wr = (wave >> 1) * 32, wc = (wave & 1) * 32;
  int lr = lane & 15, kq = (lane >> 4) * 8;

  floatx4 acc[2][2];
#pragma unroll
  for (int i = 0; i < 2; ++i)
#pragma unroll
    for (int j = 0; j < 2; ++j)
#pragma unroll
      for (int r = 0; r < 4; ++r) acc[i][j][r] = 0.f;

  for (int k0 = 0; k0 < g.K; k0 += 32) {
    {  // stage A (fp32 -> bf16): 64 rows x 32 k
      int r = tid >> 2, kc = (tid & 3) * 8;
      const float* ap = A + (long)(m0 + r) * g.lda + k0 + kc;
      float4 a0 = *(const float4*)ap;
      float4 a1 = *(const float4*)(ap + 4);
      union { unsigned short s[8]; uint4 v; } u;
      u.s[0] = to_bf16(a0.x); u.s[1] = to_bf16(a0.y); u.s[2] = to_bf16(a0.z); u.s[3] = to_bf16(a0.w);
      u.s[4] = to_bf16(a1.x); u.s[5] = to_bf16(a1.y); u.s[6] = to_bf16(a1.z); u.s[7] = to_bf16(a1.w);
      *(uint4*)&As[r][kc] = u.v;
    }
    if (g.bmode == 0) {
      int n = tid >> 2, kc = (tid & 3) * 8;
      uint4 bv = *(const uint4*)(Bt + (long)(n0 + n) * g.ldb + k0 + kc);
      *(uint4*)&Bs[n][kc] = bv;
    } else if (g.bmode == 1) {
      int n = tid >> 2, kc = (tid & 3) * 8;
      const float* bp = Bf + (long)(n0 + n) * g.ldb + k0 + kc;
      float4 b0 = *(const float4*)bp;
      float4 b1 = *(const float4*)(bp + 4);
      union { unsigned short s[8]; uint4 v; } u;
      u.s[0] = to_bf16(b0.x); u.s[1] = to_bf16(b0.y); u.s[2] = to_bf16(b0.z); u.s[3] = to_bf16(b0.w);
      u.s[4] = to_bf16(b1.x); u.s[5] = to_bf16(b1.y); u.s[6] = to_bf16(b1.z); u.s[7] = to_bf16(b1.w);
      *(uint4*)&Bs[n][kc] = u.v;
    } else {
      int kk = tid >> 3, nc = (tid & 7) * 8;
      const float* bp = Bf + (long)(k0 + kk) * g.ldb + n0 + nc;
      float4 b0 = *(const float4*)bp;
      float4 b1 = *(const float4*)(bp + 4);
      Bs[nc + 0][kk] = to_bf16(b0.x); Bs[nc + 1][kk] = to_bf16(b0.y);
      Bs[nc + 2][kk] = to_bf16(b0.z); Bs[nc + 3][kk] = to_bf16(b0.w);
      Bs[nc + 4][kk] = to_bf16(b1.x); Bs[nc + 5][kk] = to_bf16(b1.y);
      Bs[nc + 6][kk] = to_bf16(b1.z); Bs[nc + 7][kk] = to_bf16(b1.w);
    }
    __syncthreads();
    short8 a0s = *(const short8*)&As[wr + lr][kq];
    short8 a1s = *(const short8*)&As[wr + 16 + lr][kq];
    short8 b0s = *(const short8*)&Bs[wc + lr][kq];
    short8 b1s = *(const short8*)&Bs[wc + 16 + lr][kq];
    bf16x8 a0 = __builtin_bit_cast(bf16x8, a0s);
    bf16x8 a1 = __builtin_bit_cast(bf16x8, a1s);
    bf16x8 b0 = __builtin_bit_cast(bf16x8, b0s);
    bf16x8 b1 = __builtin_bit_cast(bf16x8, b1s);
    acc[0][0] = __builtin_amdgcn_mfma_f32_16x16x32_bf16(a0, b0, acc[0][0], 0, 0, 0);
    acc[0][1] = __builtin_amdgcn_mfma_f32_16x16x32_bf16(a0, b1, acc[0][1], 0, 0, 0);
    acc[1][0] = __builtin_amdgcn_mfma_f32_16x16x32_bf16(a1, b0, acc[1][0], 0, 0, 0);
    acc[1][1] = __builtin_amdgcn_mfma_f32_16x16x32_bf16(a1, b1, acc[1][1], 0, 0, 0);
    __syncthreads();
  }

  int qrow = lane >> 4;
#pragma unroll
  for (int mt = 0; mt < 2; ++mt)
#pragma unroll
    for (int nt = 0; nt < 2; ++nt)
#pragma unroll
      for (int r = 0; r < 4; ++r) {
        int row = m0 + wr + mt * 16 + qrow * 4 + r;
        int col = n0 + wc + nt * 16 + lr;
        float v = acc[mt][nt][r] * g.alpha;
        if (g.smode) {
          int oc = col + row - 511;  // rel-pos shift: j -> key position
          if (oc >= 0 && oc < g.N) C[(long)row * g.ldc + oc] += v;
        } else {
          if (g.bias) v += g.bias[col];
          if (res) v += res[(long)row * g.ldres + col];
          if (g.act) v = 0.5f * v * (1.0f + erff(v * 0.70710678118654752f));
          C[(long)row * g.ldc + col] = v;
        }
      }
}

__global__ __launch_bounds__(256) void embed_k(const int* __restrict__ trg,
                                               const float* __restrict__ embed,
                                               float* __restrict__ x) {
  int i = blockIdx.x * 256 + threadIdx.x;
  int row = i >> 9, d = i & 511;
  x[i] = embed[(long)trg[row] * 512 + d];
}

__global__ __launch_bounds__(256) void softmax_k(float* __restrict__ S, int width) {
  long row = blockIdx.x;
  float* p = S + row * (long)width;
  int tid = threadIdx.x;
  __shared__ float red[256];
  float m = -1e30f;
  for (int i = tid; i < width; i += 256) m = fmaxf(m, p[i]);
  red[tid] = m; __syncthreads();
  for (int o = 128; o > 0; o >>= 1) { if (tid < o) red[tid] = fmaxf(red[tid], red[tid + o]); __syncthreads(); }
  m = red[0]; __syncthreads();
  float s = 0.f;
  for (int i = tid; i < width; i += 256) { float e = __expf(p[i] - m); p[i] = e; s += e; }
  red[tid] = s; __syncthreads();
  for (int o = 128; o > 0; o >>= 1) { if (tid < o) red[tid] += red[tid + o]; __syncthreads(); }
  float inv = 1.f / red[0];
  for (int i = tid; i < width; i += 256) p[i] *= inv;
}

__global__ __launch_bounds__(256) void layernorm_k(const float* __restrict__ X,
                                                   const float* __restrict__ g,
                                                   const float* __restrict__ b,
                                                   float* __restrict__ Y) {
  long row = blockIdx.x;
  const float* x = X + row * 512;
  int tid = threadIdx.x;
  float v0 = x[tid], v1 = x[tid + 256];
  __shared__ float red[256];
  red[tid] = v0 + v1; __syncthreads();
  for (int o = 128; o > 0; o >>= 1) { if (tid < o) red[tid] += red[tid + o]; __syncthreads(); }
  float mu = red[0] * (1.f / 512.f);
  __syncthreads();
  float d0 = v0 - mu, d1 = v1 - mu;
  red[tid] = d0 * d0 + d1 * d1; __syncthreads();
  for (int o = 128; o > 0; o >>= 1) { if (tid < o) red[tid] += red[tid + o]; __syncthreads(); }
  float rstd = rsqrtf(red[0] * (1.f / 512.f) + 1e-5f);
  Y[row * 512 + tid] = d0 * rstd * g[tid] + b[tid];
  Y[row * 512 + tid + 256] = d1 * rstd * g[tid + 256] + b[tid + 256];
}

__global__ __launch_bounds__(256) void loss_k(const float* __restrict__ a,
                                              const float* __restrict__ b,
                                              float* __restrict__ acc) {
  int i = blockIdx.x * 256 + threadIdx.x;
  float d = a[i] - b[i];
  __shared__ float red[256];
  red[threadIdx.x] = d * d; __syncthreads();
  for (int o = 128; o > 0; o >>= 1) { if (threadIdx.x < o) red[threadIdx.x] += red[threadIdx.x + o]; __syncthreads(); }
  if (threadIdx.x == 0) atomicAdd(acc, red[0]);
}

// out[z][n][k] = bf16(in[z][k][n])
__global__ __launch_bounds__(256) void transpose_bf16_k(const float* __restrict__ in,
                                                        unsigned short* __restrict__ out,
                                                        int K, int N) {
  long z = blockIdx.z;
  in += z * (long)K * N; out += z * (long)K * N;
  __shared__ float t[32][33];
  int n0 = blockIdx.x * 32, k0 = blockIdx.y * 32;
  int tx = threadIdx.x, ty = threadIdx.y;
  for (int j = 0; j < 32; j += 8) t[ty + j][tx] = in[(long)(k0 + ty + j) * N + n0 + tx];
  __syncthreads();
  for (int j = 0; j < 32; j += 8) out[(long)(n0 + ty + j) * K + k0 + tx] = to_bf16(t[tx][ty + j]);
}

// out[z][o][r*512+d] = bf16(in[z][o][d][r])   (conv weight as [n=o][k=r*512+d])
__global__ __launch_bounds__(256) void convw_k(const float* __restrict__ in,
                                               unsigned short* __restrict__ out) {
  int i = blockIdx.x * 256 + threadIdx.x;  // [0, 1048576)
  long z = blockIdx.z;
  int o = i >> 11, k = i & 2047;
  int r = k >> 9, d = k & 511;
  out[z * 1048576 + i] = to_bf16(in[z * 1048576 + o * 2048 + d * 4 + r]);
}

__global__ __launch_bounds__(256) void cvt_bf16_k(const float* __restrict__ in,
                                                  unsigned short* __restrict__ out, int n) {
  int i = blockIdx.x * 256 + threadIdx.x;
  if (i < n) out[i] = to_bf16(in[i]);
}

__global__ __launch_bounds__(256) void finalize_k(const float* __restrict__ x,
                                                  const float* __restrict__ loss,
                                                  float* __restrict__ out) {
  long i = (long)blockIdx.x * 256 + threadIdx.x;
  if (i < 1048576) out[i] = x[i];
  else if (i == 1048576) out[i] = loss[0] * (1.f / (1048576.f * 4.f));
}

extern "C" void kernel_launch(void* const* d_in, const int* in_sizes, int n_in,
                              void* d_out, int out_size, void* d_ws, size_t ws_size,
                              hipStream_t stream) {
  (void)in_sizes; (void)n_in; (void)out_size;
  const int* trg = (const int*)d_in[0];
  const float* latent = (const float*)d_in[3];
  const float* mems = (const float*)d_in[4];
  const float* cmems = (const float*)d_in[5];
  const float* pos_emb = (const float*)d_in[6];
  const float* embed = (const float*)d_in[7];
  const float* W_self = (const float*)d_in[8];
  const float* ln1_g = (const float*)d_in[9];
  const float* ln1_b = (const float*)d_in[10];
  const float* conv_w = (const float*)d_in[11];
  const float* conv_b = (const float*)d_in[12];
  const float* W_src = (const float*)d_in[13];
  const float* ln2_g = (const float*)d_in[14];
  const float* ln2_b = (const float*)d_in[15];
  const float* w1 = (const float*)d_in[16];
  const float* b1 = (const float*)d_in[17];
  const float* w2 = (const float*)d_in[18];
  const float* b2 = (const float*)d_in[19];

  float* ws = (float*)d_ws;
  long off = 0;
  auto alloc = [&](long n) { float* p = ws + off; off += (n + 63) & ~63L; return p; };
  float* x    = alloc(1048576);
  float* xa   = alloc(1048576);
  float* t0   = alloc(1048576);   // xc
  float* t1   = alloc(1048576);   // ta / yb
  float* acat = alloc(1048576);
  float* qb   = alloc(1048576);
  float* kb   = alloc(2359296);   // [b][1152][512] (self) or [b*512][512] (rattn)
  float* vb   = alloc(2359296);
  float* h1   = alloc(4194304);
  float* ncm  = alloc(262144);
  float* kcm  = alloc(262144);
  float* vcm  = alloc(262144);
  float* ocm  = alloc(1048576);
  float* oold = alloc(1048576);
  float* klat = alloc(524288);
  float* vlat = alloc(524288);
  float* scb  = alloc(8388608);   // shared score buffer (32 MB)
  unsigned short* wtself = (unsigned short*)alloc(2097152);  // 16 x [512][512] bf16
  unsigned short* wtsrc  = (unsigned short*)alloc(2097152);
  unsigned short* w1t    = (unsigned short*)alloc(2097152);  // 4 x [2048][512]
  unsigned short* w2t    = (unsigned short*)alloc(2097152);  // 4 x [512][2048]
  unsigned short* cwt    = (unsigned short*)alloc(2097152);  // 4 x [512][2048]
  unsigned short* post   = (unsigned short*)alloc(294912);   // [8][1152][64]
  float* lossacc = alloc(64);
  if ((size_t)off * 4 > ws_size) return;  // ws guard: fail clean, not with a fault

  hipMemsetAsync(lossacc, 0, 4, stream);
  embed_k<<<4096, 256, 0, stream>>>(trg, embed, x);
  transpose_bf16_k<<<dim3(16, 16, 16), dim3(32, 8), 0, stream>>>(W_self, wtself, 512, 512);
  transpose_bf16_k<<<dim3(16, 16, 16), dim3(32, 8), 0, stream>>>(W_src, wtsrc, 512, 512);
  transpose_bf16_k<<<dim3(64, 16, 4), dim3(32, 8), 0, stream>>>(w1, w1t, 512, 2048);
  transpose_bf16_k<<<dim3(16, 64, 4), dim3(32, 8), 0, stream>>>(w2, w2t, 2048, 512);
  convw_k<<<dim3(4096, 1, 4), 256, 0, stream>>>(conv_w, cwt);
  cvt_bf16_k<<<2304, 256, 0, stream>>>(pos_emb, post, 589824);

  auto gemm = [&](const float* A, int lda, long sA1, long sA2,
                  const void* B, int ldb, long sB1, long sB2, int bmode,
                  float* C, int ldc, long sC1, long sC2,
                  int M, int N, int K, int batch, int bdiv, float alpha,
                  const float* bias, const float* res, int ldres, long sR1, long sR2,
                  int act, int smode) {
    GemmArgs g;
    g.A = A; g.lda = lda; g.sA1 = sA1; g.sA2 = sA2;
    g.B = B; g.ldb = ldb; g.sB1 = sB1; g.sB2 = sB2;
    g.C = C; g.ldc = ldc; g.sC1 = sC1; g.sC2 = sC2;
    g.M = M; g.N = N; g.K = K; g.alpha = alpha;
    g.bias = bias; g.res = res; g.ldres = ldres; g.sR1 = sR1; g.sR2 = sR2;
    g.bmode = bmode; g.act = act; g.bdiv = bdiv; g.smode = smode;
    gemm_k<<<dim3(N / 64, M / 64, batch), 256, 0, stream>>>(g);
  };

  for (int l = 0; l < 4; ++l) {
    const unsigned short* Wt0 = wtself + (l * 4 + 0) * 262144;
    const unsigned short* Wt1 = wtself + (l * 4 + 1) * 262144;
    const unsigned short* Wt2 = wtself + (l * 4 + 2) * 262144;
    const unsigned short* Wt3 = wtself + (l * 4 + 3) * 262144;
    const unsigned short* Ws0 = wtsrc + (l * 4 + 0) * 262144;
    const unsigned short* Ws1 = wtsrc + (l * 4 + 1) * 262144;
    const unsigned short* Ws2 = wtsrc + (l * 4 + 2) * 262144;
    const unsigned short* Ws3 = wtsrc + (l * 4 + 3) * 262144;
    const float* mem_l = mems + (long)l * 1048576;   // [4][512][512]
    const float* cmem_l = cmems + (long)l * 262144;  // [4][128][512]

    // ---- self-attention ----
    gemm(x, 512, 0, 0, Wt0, 512, 0, 0, 0, qb, 512, 0, 0, 2048, 512, 512, 1, 1, 1.f,
         nullptr, nullptr, 0, 0, 0, 0, 0);
    // K/V of concat(cmem, mem, x) projected directly into row-blocks of kb/vb
    gemm(cmem_l, 512, 65536, 0, Wt1, 512, 0, 0, 0, kb, 512, 589824, 0, 128, 512, 512, 4, 1, 1.f,
         nullptr, nullptr, 0, 0, 0, 0, 0);
    gemm(mem_l, 512, 262144, 0, Wt1, 512, 0, 0, 0, kb + 65536, 512, 589824, 0, 512, 512, 512, 4, 1, 1.f,
         nullptr, nullptr, 0, 0, 0, 0, 0);
    gemm(x, 512, 262144, 0, Wt1, 512, 0, 0, 0, kb + 327680, 512, 589824, 0, 512, 512, 512, 4, 1, 1.f,
         nullptr, nullptr, 0, 0, 0, 0, 0);
    gemm(cmem_l, 512, 65536, 0, Wt2, 512, 0, 0, 0, vb, 512, 589824, 0, 128, 512, 512, 4, 1, 1.f,
         nullptr, nullptr, 0, 0, 0, 0, 0);
    gemm(mem_l, 512, 262144, 0, Wt2, 512, 0, 0, 0, vb + 65536, 512, 589824, 0, 512, 512, 512, 4, 1, 1.f,
         nullptr, nullptr, 0, 0, 0, 0, 0);
    gemm(x, 512, 262144, 0, Wt2, 512, 0, 0, 0, vb + 327680, 512, 589824, 0, 512, 512, 512, 4, 1, 1.f,
         nullptr, nullptr, 0, 0, 0, 0, 0);
    for (int b = 0; b < 4; ++b) {
      // scores = qk/8 into scb[h][512][1152]
      gemm(qb + b * 262144, 512, 0, 64, kb + b * 589824, 512, 0, 64, 1,
           scb, 1152, 0, 589824, 512, 1152, 64, 8, 8, 0.125f,
           nullptr, nullptr, 0, 0, 0, 0, 0);
      // += shifted 8*(q . pos_emb) via scatter-add epilogue
      gemm(qb + b * 262144, 512, 0, 64, post, 64, 0, 73728, 0,
           scb, 1152, 0, 589824, 512, 1152, 64, 8, 8, 8.f,
           nullptr, nullptr, 0, 0, 0, 0, 1);
      softmax_k<<<4096, 256, 0, stream>>>(scb, 1152);
      gemm(scb, 1152, 0, 589824, vb + b * 589824, 512, 0, 64, 2,
           acat + b * 262144, 512, 0, 64, 512, 64, 1152, 8, 8, 1.f,
           nullptr, nullptr, 0, 0, 0, 0, 0);
    }
    gemm(acat, 512, 0, 0, Wt3, 512, 0, 0, 0, t1, 512, 0, 0, 2048, 512, 512, 1, 1, 1.f,
         nullptr, x, 512, 0, 0, 0, 0);
    layernorm_k<<<2048, 256, 0, stream>>>(t1, ln1_g + l * 512, ln1_b + l * 512, xa);

    // ---- conv compress: [B*128][2048] @ cwt^T + bias ----
    gemm(mem_l, 2048, 0, 0, cwt + (long)l * 1048576, 2048, 0, 0, 0, ncm, 512, 0, 0,
         512, 512, 2048, 1, 1, 1.f, conv_b + l * 512, nullptr, 0, 0, 0, 0, 0);

    // ---- rattn (attn-reconstruction loss) ----
    gemm(xa, 512, 0, 0, Wt0, 512, 0, 0, 0, qb, 512, 0, 0, 2048, 512, 512, 1, 1, 1.f,
         nullptr, nullptr, 0, 0, 0, 0, 0);
    gemm(ncm, 512, 0, 0, Wt1, 512, 0, 0, 0, kcm, 512, 0, 0, 512, 512, 512, 1, 1, 1.f,
         nullptr, nullptr, 0, 0, 0, 0, 0);
    gemm(ncm, 512, 0, 0, Wt2, 512, 0, 0, 0, vcm, 512, 0, 0, 512, 512, 512, 1, 1, 1.f,
         nullptr, nullptr, 0, 0, 0, 0, 0);
    gemm(mem_l, 512, 0, 0, Wt1, 512, 0, 0, 0, kb, 512, 0, 0, 2048, 512, 512, 1, 1, 1.f,
         nullptr, nullptr, 0, 0, 0, 0, 0);
    gemm(mem_l, 512, 0, 0, Wt2, 512, 0, 0, 0, vb, 512, 0, 0, 2048, 512, 512, 1, 1, 1.f,
         nullptr, nullptr, 0, 0, 0, 0, 0);
    // over new_cm (128 keys)
    gemm(qb, 512, 262144, 64, kcm, 512, 65536, 64, 1, scb, 128, 524288, 65536,
         512, 128, 64, 32, 8, 0.125f, nullptr, nullptr, 0, 0, 0, 0, 0);
    softmax_k<<<16384, 256, 0, stream>>>(scb, 128);
    gemm(scb, 128, 524288, 65536, vcm, 512, 65536, 64, 2, ocm, 512, 262144, 64,
         512, 64, 128, 32, 8, 1.f, nullptr, nullptr, 0, 0, 0, 0, 0);
    // over old_mem (512 keys)
    gemm(qb, 512, 262144, 64, kb, 512, 262144, 64, 1, scb, 512, 2097152, 262144,
         512, 512, 64, 32, 8, 0.125f, nullptr, nullptr, 0, 0, 0, 0, 0);
    softmax_k<<<16384, 256, 0, stream>>>(scb, 512);
    gemm(scb, 512, 2097152, 262144, vb, 512, 262144, 64, 2, oold, 512, 262144, 64,
         512, 64, 512, 32, 8, 1.f, nullptr, nullptr, 0, 0, 0, 0, 0);
    loss_k<<<4096, 256, 0, stream>>>(ocm, oold, lossacc);

    // ---- cross attention with latent (256 keys) ----
    gemm(xa, 512, 0, 0, Ws0, 512, 0, 0, 0, qb, 512, 0, 0, 2048, 512, 512, 1, 1, 1.f,
         nullptr, nullptr, 0, 0, 0, 0, 0);
    gemm(latent, 512, 0, 0, Ws1, 512, 0, 0, 0, klat, 512, 0, 0, 1024, 512, 512, 1, 1, 1.f,
         nullptr, nullptr, 0, 0, 0, 0, 0);
    gemm(latent, 512, 0, 0, Ws2, 512, 0, 0, 0, vlat, 512, 0, 0, 1024, 512, 512, 1, 1, 1.f,
         nullptr, nullptr, 0, 0, 0, 0, 0);
    gemm(qb, 512, 262144, 64, klat, 512, 131072, 64, 1, scb, 256, 1048576, 131072,
         512, 256, 64, 32, 8, 0.125f, nullptr, nullptr, 0, 0, 0, 0, 0);
    softmax_k<<<16384, 256, 0, stream>>>(scb, 256);
    gemm(scb, 256, 1048576, 131072, vlat, 512, 131072, 64, 2, acat, 512, 262144, 64,
         512, 64, 256, 32, 8, 1.f, nullptr, nullptr, 0, 0, 0, 0, 0);
    gemm(acat, 512, 0, 0, Ws3, 512, 0, 0, 0, t0, 512, 0, 0, 2048, 512, 512, 1, 1, 1.f,
         nullptr, nullptr, 0, 0, 0, 0, 0);
    layernorm_k<<<2048, 256, 0, stream>>>(t0, ln2_g + l * 512, ln2_b + l * 512, t1);

    // ---- FF: x = t0 + gelu(t1@w1+b1)@w2 + b2 ----
    gemm(t1, 512, 0, 0, w1t + (long)l * 1048576, 512, 0, 0, 0, h1, 2048, 0, 0,
         2048, 2048, 512, 1, 1, 1.f, b1 + l * 2048, nullptr, 0, 0, 0, 1, 0);
    gemm(h1, 2048, 0, 0, w2t + (long)l * 1048576, 2048, 0, 0, 0, x, 512, 0, 0,
         2048, 512, 2048, 1, 1, 1.f, b2 + l * 512, t0, 512, 0, 0, 0, 0);
  }
  finalize_k<<<4097, 256, 0, stream>>>(x, lossacc, (float*)d_out);
}

// Round 3
// 2542.084 us; speedup vs baseline: 1.5202x; 1.5202x over previous
//
#include <hip/hip_runtime.h>
#include <math.h>

typedef float floatx4 __attribute__((ext_vector_type(4)));
typedef __bf16 bf16x8 __attribute__((ext_vector_type(8)));
typedef unsigned short u16;

#define LDK 72  // LDS row stride in ushorts for 64-wide k tiles (144B, 16B-aligned)

__device__ inline u16 to_bf16(float f) {
  union { float f; unsigned u; } v; v.f = f;
  unsigned u = v.u;
  u += 0x7FFFu + ((u >> 16) & 1u);
  return (u16)(u >> 16);
}

struct GemmArgs {
  const void* A; const void* B; void* C;
  int lda, ldb, ldc, N, Kc;
  long sA1, sA2, sB1, sB2, sC1, sC2;
  float alpha;
  const float* bias;
  int amode;   // 0: A fp32, 1: A bf16   (strides/ld in elements)
  int cmode;   // 0: fp32 C (+bias/act/smode), 1: bf16 C (+bias/act), 2: bf16 C transposed, 3: fp32 atomicAdd
  int act;     // exact gelu (cmode 0/1)
  int smode;   // rel-pos scatter add: C[row][col+row-511] += v
  int bdiv, kparts;
};

__global__ __launch_bounds__(256) void gemm_k(GemmArgs g) {
  int z = blockIdx.z;
  int kp = z % g.kparts;
  int zz = z / g.kparts;
  int zi = zz / g.bdiv, zj = zz % g.bdiv;
  long aoff = (long)zi * g.sA1 + (long)zj * g.sA2;
  long boff = (long)zi * g.sB1 + (long)zj * g.sB2;
  long coff = (long)zi * g.sC1 + (long)zj * g.sC2;
  const float* Af = (const float*)g.A + aoff;
  const u16* Ah = (const u16*)g.A + aoff;
  const u16* Bh = (const u16*)g.B + boff;

  int m0 = blockIdx.y * 64, n0 = blockIdx.x * 64;
  __shared__ u16 As[64][LDK];
  __shared__ u16 Bs[64][LDK];
  int tid = threadIdx.x;
  int wave = tid >> 6, lane = tid & 63;
  int wr = (wave >> 1) * 32, wc = (wave & 1) * 32;
  int lr = lane & 15, qrow = lane >> 4;

  floatx4 acc[2][2];
#pragma unroll
  for (int i = 0; i < 2; ++i)
#pragma unroll
    for (int j = 0; j < 2; ++j)
#pragma unroll
      for (int r = 0; r < 4; ++r) acc[i][j][r] = 0.f;

  int r = tid >> 2, kc = (tid & 3) << 4;
  int kb0 = kp * g.Kc, kb1 = kb0 + g.Kc;
  for (int k0 = kb0; k0 < kb1; k0 += 64) {
    if (g.amode == 0) {
      const float* ap = Af + (long)(m0 + r) * g.lda + k0 + kc;
      float4 a0 = *(const float4*)ap, a1 = *(const float4*)(ap + 4);
      float4 a2 = *(const float4*)(ap + 8), a3 = *(const float4*)(ap + 12);
      union { u16 s[8]; uint4 v; } u0, u1;
      u0.s[0] = to_bf16(a0.x); u0.s[1] = to_bf16(a0.y); u0.s[2] = to_bf16(a0.z); u0.s[3] = to_bf16(a0.w);
      u0.s[4] = to_bf16(a1.x); u0.s[5] = to_bf16(a1.y); u0.s[6] = to_bf16(a1.z); u0.s[7] = to_bf16(a1.w);
      u1.s[0] = to_bf16(a2.x); u1.s[1] = to_bf16(a2.y); u1.s[2] = to_bf16(a2.z); u1.s[3] = to_bf16(a2.w);
      u1.s[4] = to_bf16(a3.x); u1.s[5] = to_bf16(a3.y); u1.s[6] = to_bf16(a3.z); u1.s[7] = to_bf16(a3.w);
      *(uint4*)&As[r][kc] = u0.v; *(uint4*)&As[r][kc + 8] = u1.v;
    } else {
      const u16* ap = Ah + (long)(m0 + r) * g.lda + k0 + kc;
      *(uint4*)&As[r][kc] = *(const uint4*)ap;
      *(uint4*)&As[r][kc + 8] = *(const uint4*)(ap + 8);
    }
    {
      const u16* bp = Bh + (long)(n0 + r) * g.ldb + k0 + kc;
      *(uint4*)&Bs[r][kc] = *(const uint4*)bp;
      *(uint4*)&Bs[r][kc + 8] = *(const uint4*)(bp + 8);
    }
    __syncthreads();
#pragma unroll
    for (int ks = 0; ks < 2; ++ks) {
      int kq = ks * 32 + qrow * 8;
      bf16x8 a0 = *(const bf16x8*)&As[wr + lr][kq];
      bf16x8 a1 = *(const bf16x8*)&As[wr + 16 + lr][kq];
      bf16x8 b0 = *(const bf16x8*)&Bs[wc + lr][kq];
      bf16x8 b1 = *(const bf16x8*)&Bs[wc + 16 + lr][kq];
      acc[0][0] = __builtin_amdgcn_mfma_f32_16x16x32_bf16(a0, b0, acc[0][0], 0, 0, 0);
      acc[0][1] = __builtin_amdgcn_mfma_f32_16x16x32_bf16(a0, b1, acc[0][1], 0, 0, 0);
      acc[1][0] = __builtin_amdgcn_mfma_f32_16x16x32_bf16(a1, b0, acc[1][0], 0, 0, 0);
      acc[1][1] = __builtin_amdgcn_mfma_f32_16x16x32_bf16(a1, b1, acc[1][1], 0, 0, 0);
    }
    __syncthreads();
  }

#pragma unroll
  for (int mt = 0; mt < 2; ++mt)
#pragma unroll
    for (int nt = 0; nt < 2; ++nt) {
      int row0 = m0 + wr + mt * 16 + qrow * 4;
      int col = n0 + wc + nt * 16 + lr;
      if (g.cmode == 2) {
        ushort4 o;
        o.x = to_bf16(acc[mt][nt][0] * g.alpha);
        o.y = to_bf16(acc[mt][nt][1] * g.alpha);
        o.z = to_bf16(acc[mt][nt][2] * g.alpha);
        o.w = to_bf16(acc[mt][nt][3] * g.alpha);
        *(ushort4*)((u16*)g.C + coff + (long)col * g.ldc + row0) = o;
      } else {
#pragma unroll
        for (int rr = 0; rr < 4; ++rr) {
          int row = row0 + rr;
          float v = acc[mt][nt][rr] * g.alpha;
          if (g.cmode == 3) {
            atomicAdd((float*)g.C + coff + (long)row * g.ldc + col, v);
          } else if (g.smode) {
            int oc = col + row - 511;
            if (oc >= 0 && oc < g.N) ((float*)g.C + coff)[(long)row * g.ldc + oc] += v;
          } else {
            if (g.bias) v += g.bias[col];
            if (g.act) v = 0.5f * v * (1.0f + erff(v * 0.70710678118654752f));
            if (g.cmode == 1) ((u16*)g.C + coff)[(long)row * g.ldc + col] = to_bf16(v);
            else ((float*)g.C + coff)[(long)row * g.ldc + col] = v;
          }
        }
      }
    }
}

__global__ __launch_bounds__(256) void embed_k(const int* __restrict__ trg,
                                               const float* __restrict__ embed,
                                               float* __restrict__ x) {
  int i = blockIdx.x * 256 + threadIdx.x;
  int row = i >> 9, d = i & 511;
  x[i] = embed[(long)trg[row] * 512 + d];
}

// width-1152 softmax, one block/row; reads fp32, writes bf16 packed in place
__global__ __launch_bounds__(256) void softmax_wide_k(float* __restrict__ S) {
  long row = blockIdx.x;
  float* p = S + row * 1152;
  int tid = threadIdx.x;
  float v[5];
  float m = -1e30f;
#pragma unroll
  for (int j = 0; j < 5; ++j) {
    int i = tid + 256 * j;
    v[j] = (i < 1152) ? p[i] : -1e30f;
    m = fmaxf(m, v[j]);
  }
  __shared__ float red[256];
  red[tid] = m; __syncthreads();
  for (int o = 128; o > 0; o >>= 1) { if (tid < o) red[tid] = fmaxf(red[tid], red[tid + o]); __syncthreads(); }
  m = red[0]; __syncthreads();
  float s = 0.f;
#pragma unroll
  for (int j = 0; j < 5; ++j) { v[j] = __expf(v[j] - m); s += v[j]; }
  red[tid] = s; __syncthreads();
  for (int o = 128; o > 0; o >>= 1) { if (tid < o) red[tid] += red[tid + o]; __syncthreads(); }
  float inv = 1.f / red[0];
  u16* ph = (u16*)p;
#pragma unroll
  for (int j = 0; j < 5; ++j) { int i = tid + 256 * j; if (i < 1152) ph[i] = to_bf16(v[j] * inv); }
}

// width<=512 softmax: one wave/row, 4 rows/block; fp32 in, bf16 packed in place
__global__ __launch_bounds__(256) void softmax_wave_k(float* __restrict__ S, int width, int nv) {
  int wave = threadIdx.x >> 6, lane = threadIdx.x & 63;
  long row = (long)blockIdx.x * 4 + wave;
  float* p = S + row * width;
  float v[8];
  float m = -1e30f;
  for (int j = 0; j < nv; ++j) { v[j] = p[lane + 64 * j]; m = fmaxf(m, v[j]); }
  for (int o = 32; o > 0; o >>= 1) m = fmaxf(m, __shfl_xor(m, o, 64));
  float s = 0.f;
  for (int j = 0; j < nv; ++j) { v[j] = __expf(v[j] - m); s += v[j]; }
  for (int o = 32; o > 0; o >>= 1) s += __shfl_xor(s, o, 64);
  float inv = 1.f / s;
  u16* ph = (u16*)p;
  for (int j = 0; j < nv; ++j) ph[lane + 64 * j] = to_bf16(v[j] * inv);
}

__global__ __launch_bounds__(256) void layernorm_k(const float* __restrict__ X,
                                                   const float* __restrict__ g,
                                                   const float* __restrict__ b,
                                                   u16* __restrict__ Y) {
  long row = blockIdx.x;
  const float* x = X + row * 512;
  int tid = threadIdx.x;
  float v0 = x[tid], v1 = x[tid + 256];
  __shared__ float red[256];
  red[tid] = v0 + v1; __syncthreads();
  for (int o = 128; o > 0; o >>= 1) { if (tid < o) red[tid] += red[tid + o]; __syncthreads(); }
  float mu = red[0] * (1.f / 512.f);
  __syncthreads();
  float d0 = v0 - mu, d1 = v1 - mu;
  red[tid] = d0 * d0 + d1 * d1; __syncthreads();
  for (int o = 128; o > 0; o >>= 1) { if (tid < o) red[tid] += red[tid + o]; __syncthreads(); }
  float rstd = rsqrtf(red[0] * (1.f / 512.f) + 1e-5f);
  Y[row * 512 + tid] = to_bf16(d0 * rstd * g[tid] + b[tid]);
  Y[row * 512 + tid + 256] = to_bf16(d1 * rstd * g[tid + 256] + b[tid + 256]);
}

__global__ __launch_bounds__(256) void preset_k(float* __restrict__ C,
                                                const float* __restrict__ res,
                                                const float* __restrict__ bias, int nmask) {
  long i = (long)blockIdx.x * 256 + threadIdx.x;
  float v = 0.f;
  if (res) v += res[i];
  if (bias) v += bias[i & nmask];
  C[i] = v;
}

__global__ __launch_bounds__(256) void loss_k(const float* __restrict__ a,
                                              const float* __restrict__ b,
                                              float* __restrict__ acc) {
  int i = blockIdx.x * 256 + threadIdx.x;
  float d = a[i] - b[i];
  __shared__ float red[256];
  red[threadIdx.x] = d * d; __syncthreads();
  for (int o = 128; o > 0; o >>= 1) { if (threadIdx.x < o) red[threadIdx.x] += red[threadIdx.x + o]; __syncthreads(); }
  if (threadIdx.x == 0) atomicAdd(acc, red[0]);
}

// out[z][n][k] = bf16(in[z][k][n])
__global__ __launch_bounds__(256) void transpose_bf16_k(const float* __restrict__ in,
                                                        u16* __restrict__ out, int K, int N) {
  long z = blockIdx.z;
  in += z * (long)K * N; out += z * (long)K * N;
  __shared__ float t[32][33];
  int n0 = blockIdx.x * 32, k0 = blockIdx.y * 32;
  int tx = threadIdx.x, ty = threadIdx.y;
  for (int j = 0; j < 32; j += 8) t[ty + j][tx] = in[(long)(k0 + ty + j) * N + n0 + tx];
  __syncthreads();
  for (int j = 0; j < 32; j += 8) out[(long)(n0 + ty + j) * K + k0 + tx] = to_bf16(t[tx][ty + j]);
}

// out[z][o][r*512+d] = bf16(in[z][o][d][r])
__global__ __launch_bounds__(256) void convw_k(const float* __restrict__ in,
                                               u16* __restrict__ out) {
  int i = blockIdx.x * 256 + threadIdx.x;
  long z = blockIdx.z;
  int o = i >> 11, k = i & 2047;
  int r = k >> 9, d = k & 511;
  out[z * 1048576 + i] = to_bf16(in[z * 1048576 + o * 2048 + d * 4 + r]);
}

__global__ __launch_bounds__(256) void cvt_bf16_k(const float* __restrict__ in,
                                                  u16* __restrict__ out, int n) {
  int i = blockIdx.x * 256 + threadIdx.x;
  if (i < n) out[i] = to_bf16(in[i]);
}

__global__ __launch_bounds__(256) void finalize_k(const float* __restrict__ x,
                                                  const float* __restrict__ loss,
                                                  float* __restrict__ out) {
  long i = (long)blockIdx.x * 256 + threadIdx.x;
  if (i < 1048576) out[i] = x[i];
  else if (i == 1048576) out[i] = loss[0] * (1.f / (1048576.f * 4.f));
}

extern "C" void kernel_launch(void* const* d_in, const int* in_sizes, int n_in,
                              void* d_out, int out_size, void* d_ws, size_t ws_size,
                              hipStream_t stream) {
  (void)in_sizes; (void)n_in; (void)out_size;
  const int* trg = (const int*)d_in[0];
  const float* latent = (const float*)d_in[3];
  const float* mems = (const float*)d_in[4];
  const float* cmems = (const float*)d_in[5];
  const float* pos_emb = (const float*)d_in[6];
  const float* embed = (const float*)d_in[7];
  const float* W_self = (const float*)d_in[8];
  const float* ln1_g = (const float*)d_in[9];
  const float* ln1_b = (const float*)d_in[10];
  const float* conv_w = (const float*)d_in[11];
  const float* conv_b = (const float*)d_in[12];
  const float* W_src = (const float*)d_in[13];
  const float* ln2_g = (const float*)d_in[14];
  const float* ln2_b = (const float*)d_in[15];
  const float* w1 = (const float*)d_in[16];
  const float* b1 = (const float*)d_in[17];
  const float* w2 = (const float*)d_in[18];
  const float* b2 = (const float*)d_in[19];

  float* ws = (float*)d_ws;
  long off = 0;
  auto alloc = [&](long n) { float* p = ws + off; off += (n + 63) & ~63L; return p; };
  float* x    = alloc(1048576);
  float* t0   = alloc(1048576);
  float* t1   = alloc(1048576);
  float* acat = alloc(1048576);
  float* ncm  = alloc(262144);
  float* ocm  = alloc(1048576);
  float* oold = alloc(1048576);
  u16* h1   = (u16*)alloc(2097152);   // [2048][2048] bf16
  u16* qb   = (u16*)alloc(524288);    // [2048][512] bf16
  u16* xa   = (u16*)alloc(524288);
  u16* t1h  = (u16*)alloc(524288);
  u16* kbuf = (u16*)alloc(1179648);   // self: [4][1152][512]; rattn: [2048][512]
  u16* vbuf = (u16*)alloc(1179648);   // self: [4][512][1152] V^T; rattn: [512][2048] V^T
  u16* kcm  = (u16*)alloc(131072);    // [512][512]
  u16* vcm  = (u16*)alloc(131072);    // [512][512] V^T
  u16* klat = (u16*)alloc(262144);    // [1024][512]
  u16* vlat = (u16*)alloc(262144);    // [512][1024] V^T
  float* scb = alloc(9437184);        // 37.7 MB score buffer
  u16* wts  = (u16*)alloc(2097152);   // 16 x [512][512]
  u16* wsr  = (u16*)alloc(2097152);
  u16* w1t  = (u16*)alloc(2097152);   // 4 x [2048][512]
  u16* w2t  = (u16*)alloc(2097152);   // 4 x [512][2048]
  u16* cwt  = (u16*)alloc(2097152);   // 4 x [512][2048]
  u16* post = (u16*)alloc(147456);    // [8][1152][64]
  float* lossacc = alloc(64);
  if ((size_t)off * 4 > ws_size) return;  // clean fail instead of fault

  hipMemsetAsync(lossacc, 0, 4, stream);
  embed_k<<<4096, 256, 0, stream>>>(trg, embed, x);
  transpose_bf16_k<<<dim3(16, 16, 16), dim3(32, 8), 0, stream>>>(W_self, wts, 512, 512);
  transpose_bf16_k<<<dim3(16, 16, 16), dim3(32, 8), 0, stream>>>(W_src, wsr, 512, 512);
  transpose_bf16_k<<<dim3(64, 16, 4), dim3(32, 8), 0, stream>>>(w1, w1t, 512, 2048);
  transpose_bf16_k<<<dim3(16, 64, 4), dim3(32, 8), 0, stream>>>(w2, w2t, 2048, 512);
  convw_k<<<dim3(4096, 1, 4), 256, 0, stream>>>(conv_w, cwt);
  cvt_bf16_k<<<2304, 256, 0, stream>>>(pos_emb, post, 589824);

  auto ga = []() { GemmArgs g; g.alpha = 1.f; g.bias = nullptr; g.amode = 0; g.cmode = 0;
                   g.act = 0; g.smode = 0; g.bdiv = 1; g.kparts = 1;
                   g.sA1 = g.sA2 = g.sB1 = g.sB2 = g.sC1 = g.sC2 = 0; g.N = 0; return g; };
  auto run = [&](GemmArgs& g, int gx, int gy, int gz) {
    gemm_k<<<dim3(gx, gy, gz), 256, 0, stream>>>(g);
  };

  for (int l = 0; l < 4; ++l) {
    const u16* Wt0 = wts + (l * 4 + 0) * 262144;
    const u16* Wt1 = wts + (l * 4 + 1) * 262144;
    const u16* Wt2 = wts + (l * 4 + 2) * 262144;
    const u16* Wt3 = wts + (l * 4 + 3) * 262144;
    const u16* Ws0 = wsr + (l * 4 + 0) * 262144;
    const u16* Ws1 = wsr + (l * 4 + 1) * 262144;
    const u16* Ws2 = wsr + (l * 4 + 2) * 262144;
    const u16* Ws3 = wsr + (l * 4 + 3) * 262144;
    const float* mem_l = mems + (long)l * 1048576;
    const float* cmem_l = cmems + (long)l * 262144;

    // ===== self-attention =====
    { GemmArgs g = ga(); g.A = x; g.lda = 512; g.B = Wt0; g.ldb = 512; g.C = qb; g.ldc = 512;
      g.cmode = 1; g.Kc = 512; run(g, 8, 32, 1); }
    // K projections of concat(cmem, mem, x) -> kbuf [b][1152][512] bf16
    { GemmArgs g = ga(); g.A = cmem_l; g.lda = 512; g.sA1 = 65536; g.B = Wt1; g.ldb = 512;
      g.C = kbuf; g.ldc = 512; g.sC1 = 589824; g.cmode = 1; g.Kc = 512; g.bdiv = 1; run(g, 8, 2, 4); }
    { GemmArgs g = ga(); g.A = mem_l; g.lda = 512; g.sA1 = 262144; g.B = Wt1; g.ldb = 512;
      g.C = kbuf + 65536; g.ldc = 512; g.sC1 = 589824; g.cmode = 1; g.Kc = 512; run(g, 8, 8, 4); }
    { GemmArgs g = ga(); g.A = x; g.lda = 512; g.sA1 = 262144; g.B = Wt1; g.ldb = 512;
      g.C = kbuf + 327680; g.ldc = 512; g.sC1 = 589824; g.cmode = 1; g.Kc = 512; run(g, 8, 8, 4); }
    // V^T projections -> vbuf [b][512][1152] bf16 (token offsets 0/128/640)
    { GemmArgs g = ga(); g.A = cmem_l; g.lda = 512; g.sA1 = 65536; g.B = Wt2; g.ldb = 512;
      g.C = vbuf; g.ldc = 1152; g.sC1 = 589824; g.cmode = 2; g.Kc = 512; run(g, 8, 2, 4); }
    { GemmArgs g = ga(); g.A = mem_l; g.lda = 512; g.sA1 = 262144; g.B = Wt2; g.ldb = 512;
      g.C = vbuf + 128; g.ldc = 1152; g.sC1 = 589824; g.cmode = 2; g.Kc = 512; run(g, 8, 8, 4); }
    { GemmArgs g = ga(); g.A = x; g.lda = 512; g.sA1 = 262144; g.B = Wt2; g.ldb = 512;
      g.C = vbuf + 640; g.ldc = 1152; g.sC1 = 589824; g.cmode = 2; g.Kc = 512; run(g, 8, 8, 4); }
    hipMemsetAsync(acat, 0, 1048576 * 4, stream);
    for (int c = 0; c < 2; ++c) {  // 2 batch samples per chunk
      // scores = qk/8 into scb fp32 [2b][8h][512][1152]
      { GemmArgs g = ga(); g.A = qb + c * 2 * 262144; g.lda = 512; g.sA1 = 262144; g.sA2 = 64;
        g.B = kbuf + c * 2 * 589824; g.ldb = 512; g.sB1 = 589824; g.sB2 = 64;
        g.C = scb; g.ldc = 1152; g.sC1 = 4718592; g.sC2 = 589824;
        g.alpha = 0.125f; g.bdiv = 8; g.Kc = 64; g.N = 1152; run(g, 18, 8, 16); }
      // += shifted 8*(q.pos)
      { GemmArgs g = ga(); g.A = qb + c * 2 * 262144; g.lda = 512; g.sA1 = 262144; g.sA2 = 64;
        g.B = post; g.ldb = 64; g.sB1 = 0; g.sB2 = 73728;
        g.C = scb; g.ldc = 1152; g.sC1 = 4718592; g.sC2 = 589824;
        g.alpha = 8.f; g.smode = 1; g.bdiv = 8; g.Kc = 64; g.N = 1152; run(g, 18, 8, 16); }
      softmax_wide_k<<<8192, 256, 0, stream>>>(scb);
      // attn @ V^T -> acat (atomic, split-K 6)
      { GemmArgs g = ga(); g.A = scb; g.amode = 1; g.lda = 2304; g.sA1 = 9437184; g.sA2 = 1179648;
        g.B = vbuf + c * 2 * 589824; g.ldb = 1152; g.sB1 = 589824; g.sB2 = 73728;
        g.C = acat + c * 2 * 262144; g.ldc = 512; g.sC1 = 262144; g.sC2 = 64;
        g.cmode = 3; g.bdiv = 8; g.kparts = 6; g.Kc = 192; run(g, 1, 8, 96); }
    }
    preset_k<<<4096, 256, 0, stream>>>(t1, x, nullptr, 511);  // residual preset
    { GemmArgs g = ga(); g.A = acat; g.lda = 512; g.B = Wt3; g.ldb = 512; g.C = t1; g.ldc = 512;
      g.cmode = 3; g.kparts = 2; g.Kc = 256; run(g, 8, 32, 2); }
    layernorm_k<<<2048, 256, 0, stream>>>(t1, ln1_g + l * 512, ln1_b + l * 512, xa);

    // ===== conv compress =====
    preset_k<<<1024, 256, 0, stream>>>(ncm, nullptr, conv_b + l * 512, 511);
    { GemmArgs g = ga(); g.A = mem_l; g.lda = 2048; g.B = cwt + (long)l * 1048576; g.ldb = 2048;
      g.C = ncm; g.ldc = 512; g.cmode = 3; g.kparts = 8; g.Kc = 256; run(g, 8, 8, 8); }

    // ===== rattn (compression loss) =====
    { GemmArgs g = ga(); g.A = xa; g.amode = 1; g.lda = 512; g.B = Wt0; g.ldb = 512;
      g.C = qb; g.ldc = 512; g.cmode = 1; g.Kc = 512; run(g, 8, 32, 1); }
    { GemmArgs g = ga(); g.A = ncm; g.lda = 512; g.B = Wt1; g.ldb = 512;
      g.C = kcm; g.ldc = 512; g.cmode = 1; g.Kc = 512; run(g, 8, 8, 1); }
    { GemmArgs g = ga(); g.A = ncm; g.lda = 512; g.B = Wt2; g.ldb = 512;
      g.C = vcm; g.ldc = 512; g.cmode = 2; g.Kc = 512; run(g, 8, 8, 1); }
    { GemmArgs g = ga(); g.A = mem_l; g.lda = 512; g.B = Wt1; g.ldb = 512;
      g.C = kbuf; g.ldc = 512; g.cmode = 1; g.Kc = 512; run(g, 8, 32, 1); }
    { GemmArgs g = ga(); g.A = mem_l; g.lda = 512; g.B = Wt2; g.ldb = 512;
      g.C = vbuf; g.ldc = 2048; g.cmode = 2; g.Kc = 512; run(g, 8, 32, 1); }
    // scores over new_cm (128 keys)
    { GemmArgs g = ga(); g.A = qb; g.amode = 1; g.lda = 512; g.sA1 = 262144; g.sA2 = 64;
      g.B = kcm; g.ldb = 512; g.sB1 = 65536; g.sB2 = 64;
      g.C = scb; g.ldc = 128; g.sC1 = 524288; g.sC2 = 65536;
      g.alpha = 0.125f; g.bdiv = 8; g.Kc = 64; run(g, 2, 8, 32); }
    softmax_wave_k<<<4096, 256, 0, stream>>>(scb, 128, 2);
    hipMemsetAsync(ocm, 0, 1048576 * 4, stream);
    { GemmArgs g = ga(); g.A = scb; g.amode = 1; g.lda = 256; g.sA1 = 1048576; g.sA2 = 131072;
      g.B = vcm; g.ldb = 512; g.sB1 = 128; g.sB2 = 32768;
      g.C = ocm; g.ldc = 512; g.sC1 = 262144; g.sC2 = 64;
      g.cmode = 3; g.bdiv = 8; g.kparts = 2; g.Kc = 64; run(g, 1, 8, 64); }
    // scores over old_mem (512 keys)
    { GemmArgs g = ga(); g.A = qb; g.amode = 1; g.lda = 512; g.sA1 = 262144; g.sA2 = 64;
      g.B = kbuf; g.ldb = 512; g.sB1 = 262144; g.sB2 = 64;
      g.C = scb; g.ldc = 512; g.sC1 = 2097152; g.sC2 = 262144;
      g.alpha = 0.125f; g.bdiv = 8; g.Kc = 64; run(g, 8, 8, 32); }
    softmax_wave_k<<<4096, 256, 0, stream>>>(scb, 512, 8);
    hipMemsetAsync(oold, 0, 1048576 * 4, stream);
    { GemmArgs g = ga(); g.A = scb; g.amode = 1; g.lda = 1024; g.sA1 = 4194304; g.sA2 = 524288;
      g.B = vbuf; g.ldb = 2048; g.sB1 = 512; g.sB2 = 131072;
      g.C = oold; g.ldc = 512; g.sC1 = 262144; g.sC2 = 64;
      g.cmode = 3; g.bdiv = 8; g.kparts = 4; g.Kc = 128; run(g, 1, 8, 128); }
    loss_k<<<4096, 256, 0, stream>>>(ocm, oold, lossacc);

    // ===== cross attention (256 latent keys) =====
    { GemmArgs g = ga(); g.A = xa; g.amode = 1; g.lda = 512; g.B = Ws0; g.ldb = 512;
      g.C = qb; g.ldc = 512; g.cmode = 1; g.Kc = 512; run(g, 8, 32, 1); }
    { GemmArgs g = ga(); g.A = latent; g.lda = 512; g.B = Ws1; g.ldb = 512;
      g.C = klat; g.ldc = 512; g.cmode = 1; g.Kc = 512; run(g, 8, 16, 1); }
    { GemmArgs g = ga(); g.A = latent; g.lda = 512; g.B = Ws2; g.ldb = 512;
      g.C = vlat; g.ldc = 1024; g.cmode = 2; g.Kc = 512; run(g, 8, 16, 1); }
    { GemmArgs g = ga(); g.A = qb; g.amode = 1; g.lda = 512; g.sA1 = 262144; g.sA2 = 64;
      g.B = klat; g.ldb = 512; g.sB1 = 131072; g.sB2 = 64;
      g.C = scb; g.ldc = 256; g.sC1 = 1048576; g.sC2 = 131072;
      g.alpha = 0.125f; g.bdiv = 8; g.Kc = 64; run(g, 4, 8, 32); }
    softmax_wave_k<<<4096, 256, 0, stream>>>(scb, 256, 4);
    hipMemsetAsync(acat, 0, 1048576 * 4, stream);
    { GemmArgs g = ga(); g.A = scb; g.amode = 1; g.lda = 512; g.sA1 = 2097152; g.sA2 = 262144;
      g.B = vlat; g.ldb = 1024; g.sB1 = 256; g.sB2 = 65536;
      g.C = acat; g.ldc = 512; g.sC1 = 262144; g.sC2 = 64;
      g.cmode = 3; g.bdiv = 8; g.kparts = 4; g.Kc = 64; run(g, 1, 8, 128); }
    hipMemsetAsync(t0, 0, 1048576 * 4, stream);
    { GemmArgs g = ga(); g.A = acat; g.lda = 512; g.B = Ws3; g.ldb = 512; g.C = t0; g.ldc = 512;
      g.cmode = 3; g.kparts = 2; g.Kc = 256; run(g, 8, 32, 2); }
    layernorm_k<<<2048, 256, 0, stream>>>(t0, ln2_g + l * 512, ln2_b + l * 512, t1h);

    // ===== FF =====
    { GemmArgs g = ga(); g.A = t1h; g.amode = 1; g.lda = 512; g.B = w1t + (long)l * 1048576; g.ldb = 512;
      g.C = h1; g.ldc = 2048; g.cmode = 1; g.bias = b1 + l * 2048; g.act = 1; g.Kc = 512;
      run(g, 32, 32, 1); }
    preset_k<<<4096, 256, 0, stream>>>(x, t0, b2 + l * 512, 511);
    { GemmArgs g = ga(); g.A = h1; g.amode = 1; g.lda = 2048; g.B = w2t + (long)l * 1048576; g.ldb = 2048;
      g.C = x; g.ldc = 512; g.cmode = 3; g.kparts = 4; g.Kc = 512; run(g, 8, 32, 4); }
  }
  finalize_k<<<4097, 256, 0, stream>>>(x, lossacc, (float*)d_out);
}

// Round 4
// 2075.698 us; speedup vs baseline: 1.8617x; 1.2247x over previous
//
#include <hip/hip_runtime.h>
#include <math.h>

typedef float floatx4 __attribute__((ext_vector_type(4)));
typedef __bf16 bf16x8 __attribute__((ext_vector_type(8)));
typedef unsigned short u16;

#define LDK 72  // LDS row stride in ushorts (144B, 16B-aligned)

__device__ inline u16 to_bf16(float f) {
  union { float f; unsigned u; } v; v.f = f;
  unsigned u = v.u;
  u += 0x7FFFu + ((u >> 16) & 1u);
  return (u16)(u >> 16);
}

struct GemmArgs {
  const void* A; const void* B; void* C;
  int lda, ldb, ldc, N, Kc;
  long sA1, sA2, sB1, sB2, sC1, sC2;
  float alpha;
  const float* bias;
  const float* res; int ldres;
  int amode;   // 0: A fp32, 1: A bf16
  int cmode;   // 0: fp32 C (+bias/res/act/smode), 1: bf16 C (+bias/act), 2: bf16 C transposed, 3: fp32 atomicAdd
  int act;     // exact gelu
  int smode;   // rel-pos scatter add: C[row][col+row-511] += v
  int bdiv, kparts;
};

__global__ __launch_bounds__(256) void gemm_k(GemmArgs g) {
  int z = blockIdx.z;
  int kp = z % g.kparts;
  int zz = z / g.kparts;
  int zi = zz / g.bdiv, zj = zz % g.bdiv;
  long aoff = (long)zi * g.sA1 + (long)zj * g.sA2;
  long boff = (long)zi * g.sB1 + (long)zj * g.sB2;
  long coff = (long)zi * g.sC1 + (long)zj * g.sC2;
  const float* Af = (const float*)g.A + aoff;
  const u16* Ah = (const u16*)g.A + aoff;
  const u16* Bh = (const u16*)g.B + boff;

  int m0 = blockIdx.y * 64, n0 = blockIdx.x * 64;
  __shared__ u16 As[64][LDK];
  __shared__ u16 Bs[64][LDK];
  int tid = threadIdx.x;
  int wave = tid >> 6, lane = tid & 63;
  int wr = (wave >> 1) * 32, wc = (wave & 1) * 32;
  int lr = lane & 15, qrow = lane >> 4;

  floatx4 acc[2][2];
#pragma unroll
  for (int i = 0; i < 2; ++i)
#pragma unroll
    for (int j = 0; j < 2; ++j)
#pragma unroll
      for (int r = 0; r < 4; ++r) acc[i][j][r] = 0.f;

  int r = tid >> 2, kc = (tid & 3) << 4;
  int kb0 = kp * g.Kc, kb1 = kb0 + g.Kc;
  for (int k0 = kb0; k0 < kb1; k0 += 64) {
    if (g.amode == 0) {
      const float* ap = Af + (long)(m0 + r) * g.lda + k0 + kc;
      float4 a0 = *(const float4*)ap, a1 = *(const float4*)(ap + 4);
      float4 a2 = *(const float4*)(ap + 8), a3 = *(const float4*)(ap + 12);
      union { u16 s[8]; uint4 v; } u0, u1;
      u0.s[0] = to_bf16(a0.x); u0.s[1] = to_bf16(a0.y); u0.s[2] = to_bf16(a0.z); u0.s[3] = to_bf16(a0.w);
      u0.s[4] = to_bf16(a1.x); u0.s[5] = to_bf16(a1.y); u0.s[6] = to_bf16(a1.z); u0.s[7] = to_bf16(a1.w);
      u1.s[0] = to_bf16(a2.x); u1.s[1] = to_bf16(a2.y); u1.s[2] = to_bf16(a2.z); u1.s[3] = to_bf16(a2.w);
      u1.s[4] = to_bf16(a3.x); u1.s[5] = to_bf16(a3.y); u1.s[6] = to_bf16(a3.z); u1.s[7] = to_bf16(a3.w);
      *(uint4*)&As[r][kc] = u0.v; *(uint4*)&As[r][kc + 8] = u1.v;
    } else {
      const u16* ap = Ah + (long)(m0 + r) * g.lda + k0 + kc;
      *(uint4*)&As[r][kc] = *(const uint4*)ap;
      *(uint4*)&As[r][kc + 8] = *(const uint4*)(ap + 8);
    }
    {
      const u16* bp = Bh + (long)(n0 + r) * g.ldb + k0 + kc;
      *(uint4*)&Bs[r][kc] = *(const uint4*)bp;
      *(uint4*)&Bs[r][kc + 8] = *(const uint4*)(bp + 8);
    }
    __syncthreads();
#pragma unroll
    for (int ks = 0; ks < 2; ++ks) {
      int kq = ks * 32 + qrow * 8;
      bf16x8 a0 = *(const bf16x8*)&As[wr + lr][kq];
      bf16x8 a1 = *(const bf16x8*)&As[wr + 16 + lr][kq];
      bf16x8 b0 = *(const bf16x8*)&Bs[wc + lr][kq];
      bf16x8 b1 = *(const bf16x8*)&Bs[wc + 16 + lr][kq];
      acc[0][0] = __builtin_amdgcn_mfma_f32_16x16x32_bf16(a0, b0, acc[0][0], 0, 0, 0);
      acc[0][1] = __builtin_amdgcn_mfma_f32_16x16x32_bf16(a0, b1, acc[0][1], 0, 0, 0);
      acc[1][0] = __builtin_amdgcn_mfma_f32_16x16x32_bf16(a1, b0, acc[1][0], 0, 0, 0);
      acc[1][1] = __builtin_amdgcn_mfma_f32_16x16x32_bf16(a1, b1, acc[1][1], 0, 0, 0);
    }
    __syncthreads();
  }

#pragma unroll
  for (int mt = 0; mt < 2; ++mt)
#pragma unroll
    for (int nt = 0; nt < 2; ++nt) {
      int row0 = m0 + wr + mt * 16 + qrow * 4;
      int col = n0 + wc + nt * 16 + lr;
      if (g.cmode == 2) {
        ushort4 o;
        o.x = to_bf16(acc[mt][nt][0] * g.alpha);
        o.y = to_bf16(acc[mt][nt][1] * g.alpha);
        o.z = to_bf16(acc[mt][nt][2] * g.alpha);
        o.w = to_bf16(acc[mt][nt][3] * g.alpha);
        *(ushort4*)((u16*)g.C + coff + (long)col * g.ldc + row0) = o;
      } else {
#pragma unroll
        for (int rr = 0; rr < 4; ++rr) {
          int row = row0 + rr;
          float v = acc[mt][nt][rr] * g.alpha;
          if (g.cmode == 3) {
            atomicAdd((float*)g.C + coff + (long)row * g.ldc + col, v);
          } else if (g.smode) {
            int oc = col + row - 511;
            if (oc >= 0 && oc < g.N) ((float*)g.C + coff)[(long)row * g.ldc + oc] += v;
          } else {
            if (g.bias) v += g.bias[col];
            if (g.res) v += g.res[(long)row * g.ldres + col];
            if (g.act) v = 0.5f * v * (1.0f + erff(v * 0.70710678118654752f));
            if (g.cmode == 1) ((u16*)g.C + coff)[(long)row * g.ldc + col] = to_bf16(v);
            else ((float*)g.C + coff)[(long)row * g.ldc + col] = v;
          }
        }
      }
    }
}

// Fused attention, no pos-emb. One block = (qtile 64 rows, head h, sample b).
// Q: bf16 [b*512+s][512] (head at col h*64). K: bf16 [b*L+t][512].
// V^T: bf16 [h*64+d][4*L] (col b*L+t). O: fp32 [b*512+s][512], direct store.
__global__ __launch_bounds__(256) void fattn_k(const u16* __restrict__ Q,
                                               const u16* __restrict__ K,
                                               const u16* __restrict__ V,
                                               float* __restrict__ O,
                                               int L, float scale) {
  int qt = blockIdx.x, h = blockIdx.y, b = blockIdx.z;
  int tid = threadIdx.x, wave = tid >> 6, lane = tid & 63;
  int lr = lane & 15, quad = lane >> 4;
  __shared__ u16 Qs[64][LDK];
  __shared__ u16 Ks[64][LDK];
  __shared__ u16 Vs[64][LDK];
  __shared__ u16 Ps[4][16][LDK];
  int ldV = 4 * L;
  int r = tid >> 2, c = (tid & 3) << 4;
  {
    const u16* qp = Q + (long)(b * 512 + qt * 64 + r) * 512 + h * 64 + c;
    *(uint4*)&Qs[r][c] = *(const uint4*)qp;
    *(uint4*)&Qs[r][c + 8] = *(const uint4*)(qp + 8);
  }
  float m_run[4], l_run[4];
  floatx4 oacc[4];
#pragma unroll
  for (int i = 0; i < 4; ++i) {
    m_run[i] = -1e30f; l_run[i] = 0.f;
#pragma unroll
    for (int j = 0; j < 4; ++j) oacc[i][j] = 0.f;
  }

  for (int kt = 0; kt < L; kt += 64) {
    {
      const u16* kp = K + (long)(b * L + kt + r) * 512 + h * 64 + c;
      *(uint4*)&Ks[r][c] = *(const uint4*)kp;
      *(uint4*)&Ks[r][c + 8] = *(const uint4*)(kp + 8);
      const u16* vp = V + (long)(h * 64 + r) * ldV + b * L + kt + c;
      *(uint4*)&Vs[r][c] = *(const uint4*)vp;
      *(uint4*)&Vs[r][c + 8] = *(const uint4*)(vp + 8);
    }
    __syncthreads();
    // S = Q K^T : wave computes 16 q-rows x 64 kv
    floatx4 sacc[4];
#pragma unroll
    for (int nt = 0; nt < 4; ++nt)
#pragma unroll
      for (int j = 0; j < 4; ++j) sacc[nt][j] = 0.f;
#pragma unroll
    for (int ks = 0; ks < 2; ++ks) {
      int kq = ks * 32 + quad * 8;
      bf16x8 a = *(const bf16x8*)&Qs[wave * 16 + lr][kq];
#pragma unroll
      for (int nt = 0; nt < 4; ++nt) {
        bf16x8 bb = *(const bf16x8*)&Ks[nt * 16 + lr][kq];
        sacc[nt] = __builtin_amdgcn_mfma_f32_16x16x32_bf16(a, bb, sacc[nt], 0, 0, 0);
      }
    }
    // online softmax per row (row = quad*4+reg, replicated across the 16 lanes of a quad)
    float mx[4], ps[4];
#pragma unroll
    for (int rr = 0; rr < 4; ++rr) {
      float m = -1e30f;
#pragma unroll
      for (int nt = 0; nt < 4; ++nt) m = fmaxf(m, sacc[nt][rr] * scale);
      for (int o = 8; o > 0; o >>= 1) m = fmaxf(m, __shfl_xor(m, o, 64));
      mx[rr] = m;
    }
#pragma unroll
    for (int rr = 0; rr < 4; ++rr) {
      float mn = fmaxf(m_run[rr], mx[rr]);
      float al = __expf(m_run[rr] - mn);
      m_run[rr] = mn;
      float s = 0.f;
#pragma unroll
      for (int nt = 0; nt < 4; ++nt) {
        float p = __expf(sacc[nt][rr] * scale - mn);
        sacc[nt][rr] = p;  // reuse as P
        s += p;
      }
      for (int o = 8; o > 0; o >>= 1) s += __shfl_xor(s, o, 64);
      l_run[rr] = l_run[rr] * al + s;
#pragma unroll
      for (int nt = 0; nt < 4; ++nt) oacc[nt][rr] *= al;
    }
    // P (C-layout) -> LDS -> A-layout
#pragma unroll
    for (int nt = 0; nt < 4; ++nt) {
      ushort4 pw;
      pw.x = to_bf16(sacc[nt][0]); pw.y = to_bf16(sacc[nt][1]);
      pw.z = to_bf16(sacc[nt][2]); pw.w = to_bf16(sacc[nt][3]);
      // row quad*4+{0..3}, col nt*16+lr  -> store 4 rows same col (strided u16 writes)
      Ps[wave][quad * 4 + 0][nt * 16 + lr] = pw.x;
      Ps[wave][quad * 4 + 1][nt * 16 + lr] = pw.y;
      Ps[wave][quad * 4 + 2][nt * 16 + lr] = pw.z;
      Ps[wave][quad * 4 + 3][nt * 16 + lr] = pw.w;
    }
    // O += P V^T
#pragma unroll
    for (int ks = 0; ks < 2; ++ks) {
      int kq = ks * 32 + quad * 8;
      bf16x8 a = *(const bf16x8*)&Ps[wave][lr][kq];
#pragma unroll
      for (int nt = 0; nt < 4; ++nt) {
        bf16x8 bb = *(const bf16x8*)&Vs[nt * 16 + lr][kq];
        oacc[nt] = __builtin_amdgcn_mfma_f32_16x16x32_bf16(a, bb, oacc[nt], 0, 0, 0);
      }
    }
    __syncthreads();
  }
  float inv[4];
#pragma unroll
  for (int rr = 0; rr < 4; ++rr) inv[rr] = 1.f / l_run[rr];
#pragma unroll
  for (int nt = 0; nt < 4; ++nt)
#pragma unroll
    for (int rr = 0; rr < 4; ++rr) {
      int row = b * 512 + qt * 64 + wave * 16 + quad * 4 + rr;
      O[(long)row * 512 + h * 64 + nt * 16 + lr] = oacc[nt][rr] * inv[rr];
    }
}

__global__ __launch_bounds__(256) void embed_k(const int* __restrict__ trg,
                                               const float* __restrict__ embed,
                                               float* __restrict__ x) {
  int i = blockIdx.x * 256 + threadIdx.x;
  int row = i >> 9, d = i & 511;
  x[i] = embed[(long)trg[row] * 512 + d];
}

__global__ __launch_bounds__(256) void softmax_wide_k(float* __restrict__ S) {
  long row = blockIdx.x;
  float* p = S + row * 1152;
  int tid = threadIdx.x;
  float v[5];
  float m = -1e30f;
#pragma unroll
  for (int j = 0; j < 5; ++j) {
    int i = tid + 256 * j;
    v[j] = (i < 1152) ? p[i] : -1e30f;
    m = fmaxf(m, v[j]);
  }
  __shared__ float red[256];
  red[tid] = m; __syncthreads();
  for (int o = 128; o > 0; o >>= 1) { if (tid < o) red[tid] = fmaxf(red[tid], red[tid + o]); __syncthreads(); }
  m = red[0]; __syncthreads();
  float s = 0.f;
#pragma unroll
  for (int j = 0; j < 5; ++j) { v[j] = __expf(v[j] - m); s += v[j]; }
  red[tid] = s; __syncthreads();
  for (int o = 128; o > 0; o >>= 1) { if (tid < o) red[tid] += red[tid + o]; __syncthreads(); }
  float inv = 1.f / red[0];
  u16* ph = (u16*)p;
#pragma unroll
  for (int j = 0; j < 5; ++j) { int i = tid + 256 * j; if (i < 1152) ph[i] = to_bf16(v[j] * inv); }
}

__global__ __launch_bounds__(256) void layernorm_k(const float* __restrict__ X,
                                                   const float* __restrict__ g,
                                                   const float* __restrict__ b,
                                                   u16* __restrict__ Y) {
  long row = blockIdx.x;
  const float* x = X + row * 512;
  int tid = threadIdx.x;
  float v0 = x[tid], v1 = x[tid + 256];
  __shared__ float red[256];
  red[tid] = v0 + v1; __syncthreads();
  for (int o = 128; o > 0; o >>= 1) { if (tid < o) red[tid] += red[tid + o]; __syncthreads(); }
  float mu = red[0] * (1.f / 512.f);
  __syncthreads();
  float d0 = v0 - mu, d1 = v1 - mu;
  red[tid] = d0 * d0 + d1 * d1; __syncthreads();
  for (int o = 128; o > 0; o >>= 1) { if (tid < o) red[tid] += red[tid + o]; __syncthreads(); }
  float rstd = rsqrtf(red[0] * (1.f / 512.f) + 1e-5f);
  Y[row * 512 + tid] = to_bf16(d0 * rstd * g[tid] + b[tid]);
  Y[row * 512 + tid + 256] = to_bf16(d1 * rstd * g[tid + 256] + b[tid + 256]);
}

__global__ __launch_bounds__(256) void preset_k(float* __restrict__ C,
                                                const float* __restrict__ res,
                                                const float* __restrict__ bias, int nmask) {
  long i = (long)blockIdx.x * 256 + threadIdx.x;
  float v = 0.f;
  if (res) v += res[i];
  if (bias) v += bias[i & nmask];
  C[i] = v;
}

// 128 blocks, grid-stride, one atomic per block (was 4096 same-address atomics = 54 us)
__global__ __launch_bounds__(256) void loss_k(const float* __restrict__ a,
                                              const float* __restrict__ b,
                                              float* __restrict__ acc) {
  float s = 0.f;
  for (long i = (long)blockIdx.x * 256 + threadIdx.x; i < 1048576; i += 256L * 128) {
    float d = a[i] - b[i]; s += d * d;
  }
  for (int o = 32; o > 0; o >>= 1) s += __shfl_xor(s, o, 64);
  __shared__ float red[4];
  if ((threadIdx.x & 63) == 0) red[threadIdx.x >> 6] = s;
  __syncthreads();
  if (threadIdx.x == 0) atomicAdd(acc, red[0] + red[1] + red[2] + red[3]);
}

__global__ __launch_bounds__(256) void transpose_bf16_k(const float* __restrict__ in,
                                                        u16* __restrict__ out, int K, int N) {
  long z = blockIdx.z;
  in += z * (long)K * N; out += z * (long)K * N;
  __shared__ float t[32][33];
  int n0 = blockIdx.x * 32, k0 = blockIdx.y * 32;
  int tx = threadIdx.x, ty = threadIdx.y;
  for (int j = 0; j < 32; j += 8) t[ty + j][tx] = in[(long)(k0 + ty + j) * N + n0 + tx];
  __syncthreads();
  for (int j = 0; j < 32; j += 8) out[(long)(n0 + ty + j) * K + k0 + tx] = to_bf16(t[tx][ty + j]);
}

__global__ __launch_bounds__(256) void convw_k(const float* __restrict__ in,
                                               u16* __restrict__ out) {
  int i = blockIdx.x * 256 + threadIdx.x;
  long z = blockIdx.z;
  int o = i >> 11, k = i & 2047;
  int r = k >> 9, d = k & 511;
  out[z * 1048576 + i] = to_bf16(in[z * 1048576 + o * 2048 + d * 4 + r]);
}

__global__ __launch_bounds__(256) void cvt_bf16_k(const float* __restrict__ in,
                                                  u16* __restrict__ out, int n) {
  int i = blockIdx.x * 256 + threadIdx.x;
  if (i < n) out[i] = to_bf16(in[i]);
}

__global__ __launch_bounds__(256) void finalize_k(const float* __restrict__ x,
                                                  const float* __restrict__ loss,
                                                  float* __restrict__ out) {
  long i = (long)blockIdx.x * 256 + threadIdx.x;
  if (i < 1048576) out[i] = x[i];
  else if (i == 1048576) out[i] = loss[0] * (1.f / (1048576.f * 4.f));
}

extern "C" void kernel_launch(void* const* d_in, const int* in_sizes, int n_in,
                              void* d_out, int out_size, void* d_ws, size_t ws_size,
                              hipStream_t stream) {
  (void)in_sizes; (void)n_in; (void)out_size;
  const int* trg = (const int*)d_in[0];
  const float* latent = (const float*)d_in[3];
  const float* mems = (const float*)d_in[4];
  const float* cmems = (const float*)d_in[5];
  const float* pos_emb = (const float*)d_in[6];
  const float* embed = (const float*)d_in[7];
  const float* W_self = (const float*)d_in[8];
  const float* ln1_g = (const float*)d_in[9];
  const float* ln1_b = (const float*)d_in[10];
  const float* conv_w = (const float*)d_in[11];
  const float* conv_b = (const float*)d_in[12];
  const float* W_src = (const float*)d_in[13];
  const float* ln2_g = (const float*)d_in[14];
  const float* ln2_b = (const float*)d_in[15];
  const float* w1 = (const float*)d_in[16];
  const float* b1 = (const float*)d_in[17];
  const float* w2 = (const float*)d_in[18];
  const float* b2 = (const float*)d_in[19];

  float* ws = (float*)d_ws;
  long off = 0;
  auto alloc = [&](long n) { float* p = ws + off; off += (n + 63) & ~63L; return p; };
  float* x    = alloc(1048576);
  float* t0   = alloc(1048576);
  float* t1   = alloc(1048576);
  float* acat = alloc(1048576);
  float* ncm  = alloc(262144);
  float* ocm  = alloc(1048576);
  float* oold = alloc(1048576);
  u16* h1   = (u16*)alloc(2097152);
  u16* qb   = (u16*)alloc(524288);
  u16* xa   = (u16*)alloc(524288);
  u16* t1h  = (u16*)alloc(524288);
  u16* kbuf = (u16*)alloc(1179648);
  u16* vbuf = (u16*)alloc(1179648);
  u16* kcm  = (u16*)alloc(131072);
  u16* vcm  = (u16*)alloc(131072);
  u16* klat = (u16*)alloc(262144);
  u16* vlat = (u16*)alloc(262144);
  float* scb = alloc(9437184);
  u16* wts  = (u16*)alloc(2097152);
  u16* wsr  = (u16*)alloc(2097152);
  u16* w1t  = (u16*)alloc(2097152);
  u16* w2t  = (u16*)alloc(2097152);
  u16* cwt  = (u16*)alloc(2097152);
  u16* post = (u16*)alloc(147456);
  float* lossacc = alloc(64);
  if ((size_t)off * 4 > ws_size) return;

  hipMemsetAsync(lossacc, 0, 4, stream);
  embed_k<<<4096, 256, 0, stream>>>(trg, embed, x);
  transpose_bf16_k<<<dim3(16, 16, 16), dim3(32, 8), 0, stream>>>(W_self, wts, 512, 512);
  transpose_bf16_k<<<dim3(16, 16, 16), dim3(32, 8), 0, stream>>>(W_src, wsr, 512, 512);
  transpose_bf16_k<<<dim3(64, 16, 4), dim3(32, 8), 0, stream>>>(w1, w1t, 512, 2048);
  transpose_bf16_k<<<dim3(16, 64, 4), dim3(32, 8), 0, stream>>>(w2, w2t, 2048, 512);
  convw_k<<<dim3(4096, 1, 4), 256, 0, stream>>>(conv_w, cwt);
  cvt_bf16_k<<<2304, 256, 0, stream>>>(pos_emb, post, 589824);

  auto ga = []() { GemmArgs g; g.alpha = 1.f; g.bias = nullptr; g.res = nullptr; g.ldres = 512;
                   g.amode = 0; g.cmode = 0; g.act = 0; g.smode = 0; g.bdiv = 1; g.kparts = 1;
                   g.sA1 = g.sA2 = g.sB1 = g.sB2 = g.sC1 = g.sC2 = 0; g.N = 0; return g; };
  auto run = [&](GemmArgs& g, int gx, int gy, int gz) {
    gemm_k<<<dim3(gx, gy, gz), 256, 0, stream>>>(g);
  };

  for (int l = 0; l < 4; ++l) {
    const u16* Wt0 = wts + (l * 4 + 0) * 262144;
    const u16* Wt1 = wts + (l * 4 + 1) * 262144;
    const u16* Wt2 = wts + (l * 4 + 2) * 262144;
    const u16* Wt3 = wts + (l * 4 + 3) * 262144;
    const u16* Ws0 = wsr + (l * 4 + 0) * 262144;
    const u16* Ws1 = wsr + (l * 4 + 1) * 262144;
    const u16* Ws2 = wsr + (l * 4 + 2) * 262144;
    const u16* Ws3 = wsr + (l * 4 + 3) * 262144;
    const float* mem_l = mems + (long)l * 1048576;
    const float* cmem_l = cmems + (long)l * 262144;

    // ===== self-attention =====
    { GemmArgs g = ga(); g.A = x; g.lda = 512; g.B = Wt0; g.ldb = 512; g.C = qb; g.ldc = 512;
      g.cmode = 1; g.Kc = 512; run(g, 8, 32, 1); }
    { GemmArgs g = ga(); g.A = cmem_l; g.lda = 512; g.sA1 = 65536; g.B = Wt1; g.ldb = 512;
      g.C = kbuf; g.ldc = 512; g.sC1 = 589824; g.cmode = 1; g.Kc = 512; run(g, 8, 2, 4); }
    { GemmArgs g = ga(); g.A = mem_l; g.lda = 512; g.sA1 = 262144; g.B = Wt1; g.ldb = 512;
      g.C = kbuf + 65536; g.ldc = 512; g.sC1 = 589824; g.cmode = 1; g.Kc = 512; run(g, 8, 8, 4); }
    { GemmArgs g = ga(); g.A = x; g.lda = 512; g.sA1 = 262144; g.B = Wt1; g.ldb = 512;
      g.C = kbuf + 327680; g.ldc = 512; g.sC1 = 589824; g.cmode = 1; g.Kc = 512; run(g, 8, 8, 4); }
    { GemmArgs g = ga(); g.A = cmem_l; g.lda = 512; g.sA1 = 65536; g.B = Wt2; g.ldb = 512;
      g.C = vbuf; g.ldc = 1152; g.sC1 = 589824; g.cmode = 2; g.Kc = 512; run(g, 8, 2, 4); }
    { GemmArgs g = ga(); g.A = mem_l; g.lda = 512; g.sA1 = 262144; g.B = Wt2; g.ldb = 512;
      g.C = vbuf + 128; g.ldc = 1152; g.sC1 = 589824; g.cmode = 2; g.Kc = 512; run(g, 8, 8, 4); }
    { GemmArgs g = ga(); g.A = x; g.lda = 512; g.sA1 = 262144; g.B = Wt2; g.ldb = 512;
      g.C = vbuf + 640; g.ldc = 1152; g.sC1 = 589824; g.cmode = 2; g.Kc = 512; run(g, 8, 8, 4); }
    hipMemsetAsync(acat, 0, 1048576 * 4, stream);
    for (int c = 0; c < 2; ++c) {
      { GemmArgs g = ga(); g.A = qb + c * 2 * 262144; g.amode = 1; g.lda = 512; g.sA1 = 262144; g.sA2 = 64;
        g.B = kbuf + c * 2 * 589824; g.ldb = 512; g.sB1 = 589824; g.sB2 = 64;
        g.C = scb; g.ldc = 1152; g.sC1 = 4718592; g.sC2 = 589824;
        g.alpha = 0.125f; g.bdiv = 8; g.Kc = 64; g.N = 1152; run(g, 18, 8, 16); }
      { GemmArgs g = ga(); g.A = qb + c * 2 * 262144; g.amode = 1; g.lda = 512; g.sA1 = 262144; g.sA2 = 64;
        g.B = post; g.ldb = 64; g.sB1 = 0; g.sB2 = 73728;
        g.C = scb; g.ldc = 1152; g.sC1 = 4718592; g.sC2 = 589824;
        g.alpha = 8.f; g.smode = 1; g.bdiv = 8; g.Kc = 64; g.N = 1152; run(g, 18, 8, 16); }
      softmax_wide_k<<<8192, 256, 0, stream>>>(scb);
      { GemmArgs g = ga(); g.A = scb; g.amode = 1; g.lda = 2304; g.sA1 = 9437184; g.sA2 = 1179648;
        g.B = vbuf + c * 2 * 589824; g.ldb = 1152; g.sB1 = 589824; g.sB2 = 73728;
        g.C = acat + c * 2 * 262144; g.ldc = 512; g.sC1 = 262144; g.sC2 = 64;
        g.cmode = 3; g.bdiv = 8; g.kparts = 6; g.Kc = 192; run(g, 1, 8, 96); }
    }
    { GemmArgs g = ga(); g.A = acat; g.lda = 512; g.B = Wt3; g.ldb = 512; g.C = t1; g.ldc = 512;
      g.res = x; g.Kc = 512; run(g, 8, 32, 1); }
    layernorm_k<<<2048, 256, 0, stream>>>(t1, ln1_g + l * 512, ln1_b + l * 512, xa);

    // ===== conv compress =====
    preset_k<<<1024, 256, 0, stream>>>(ncm, nullptr, conv_b + l * 512, 511);
    { GemmArgs g = ga(); g.A = mem_l; g.lda = 2048; g.B = cwt + (long)l * 1048576; g.ldb = 2048;
      g.C = ncm; g.ldc = 512; g.cmode = 3; g.kparts = 8; g.Kc = 256; run(g, 8, 8, 8); }

    // ===== rattn (compression loss) =====
    { GemmArgs g = ga(); g.A = xa; g.amode = 1; g.lda = 512; g.B = Wt0; g.ldb = 512;
      g.C = qb; g.ldc = 512; g.cmode = 1; g.Kc = 512; run(g, 8, 32, 1); }
    { GemmArgs g = ga(); g.A = ncm; g.lda = 512; g.B = Wt1; g.ldb = 512;
      g.C = kcm; g.ldc = 512; g.cmode = 1; g.Kc = 512; run(g, 8, 8, 1); }
    { GemmArgs g = ga(); g.A = ncm; g.lda = 512; g.B = Wt2; g.ldb = 512;
      g.C = vcm; g.ldc = 512; g.cmode = 2; g.Kc = 512; run(g, 8, 8, 1); }
    { GemmArgs g = ga(); g.A = mem_l; g.lda = 512; g.B = Wt1; g.ldb = 512;
      g.C = kbuf; g.ldc = 512; g.cmode = 1; g.Kc = 512; run(g, 8, 32, 1); }
    { GemmArgs g = ga(); g.A = mem_l; g.lda = 512; g.B = Wt2; g.ldb = 512;
      g.C = vbuf; g.ldc = 2048; g.cmode = 2; g.Kc = 512; run(g, 8, 32, 1); }
    fattn_k<<<dim3(8, 8, 4), 256, 0, stream>>>(qb, kcm, vcm, ocm, 128, 0.125f);
    fattn_k<<<dim3(8, 8, 4), 256, 0, stream>>>(qb, kbuf, vbuf, oold, 512, 0.125f);
    loss_k<<<128, 256, 0, stream>>>(ocm, oold, lossacc);

    // ===== cross attention (256 latent keys) =====
    { GemmArgs g = ga(); g.A = xa; g.amode = 1; g.lda = 512; g.B = Ws0; g.ldb = 512;
      g.C = qb; g.ldc = 512; g.cmode = 1; g.Kc = 512; run(g, 8, 32, 1); }
    { GemmArgs g = ga(); g.A = latent; g.lda = 512; g.B = Ws1; g.ldb = 512;
      g.C = klat; g.ldc = 512; g.cmode = 1; g.Kc = 512; run(g, 8, 16, 1); }
    { GemmArgs g = ga(); g.A = latent; g.lda = 512; g.B = Ws2; g.ldb = 512;
      g.C = vlat; g.ldc = 1024; g.cmode = 2; g.Kc = 512; run(g, 8, 16, 1); }
    fattn_k<<<dim3(8, 8, 4), 256, 0, stream>>>(qb, klat, vlat, acat, 256, 0.125f);
    { GemmArgs g = ga(); g.A = acat; g.lda = 512; g.B = Ws3; g.ldb = 512; g.C = t0; g.ldc = 512;
      g.Kc = 512; run(g, 8, 32, 1); }
    layernorm_k<<<2048, 256, 0, stream>>>(t0, ln2_g + l * 512, ln2_b + l * 512, t1h);

    // ===== FF =====
    { GemmArgs g = ga(); g.A = t1h; g.amode = 1; g.lda = 512; g.B = w1t + (long)l * 1048576; g.ldb = 512;
      g.C = h1; g.ldc = 2048; g.cmode = 1; g.bias = b1 + l * 2048; g.act = 1; g.Kc = 512;
      run(g, 32, 32, 1); }
    preset_k<<<4096, 256, 0, stream>>>(x, t0, b2 + l * 512, 511);
    { GemmArgs g = ga(); g.A = h1; g.amode = 1; g.lda = 2048; g.B = w2t + (long)l * 1048576; g.ldb = 2048;
      g.C = x; g.ldc = 512; g.cmode = 3; g.kparts = 4; g.Kc = 512; run(g, 8, 32, 4); }
  }
  finalize_k<<<4097, 256, 0, stream>>>(x, lossacc, (float*)d_out);
}

// Round 5
// 1816.781 us; speedup vs baseline: 2.1270x; 1.1425x over previous
//
#include <hip/hip_runtime.h>
#include <math.h>

typedef float floatx4 __attribute__((ext_vector_type(4)));
typedef __bf16 bf16x8 __attribute__((ext_vector_type(8)));
typedef unsigned short u16;

#define LDK 72  // LDS row stride in ushorts (144B, 16B-aligned)

__device__ inline u16 to_bf16(float f) {
  union { float f; unsigned u; } v; v.f = f;
  unsigned u = v.u;
  u += 0x7FFFu + ((u >> 16) & 1u);
  return (u16)(u >> 16);
}
__device__ inline float bf2f(u16 h) {
  union { unsigned u; float f; } v; v.u = ((unsigned)h) << 16; return v.f;
}

struct GemmArgs {
  const void* A; const void* B; void* C;
  int lda, ldb, ldc, N, Kc;
  long sA1, sA2, sB1, sB2, sC1, sC2;
  float alpha;
  const float* bias;
  const float* res; int ldres;
  int amode;   // 0: A fp32, 1: A bf16
  int cmode;   // 0: fp32 C (+bias/res/act), 1: bf16 C (+bias/act), 2: bf16 C transposed, 3: fp32 atomicAdd
  int act;     // exact gelu
  int bdiv, kparts;
};

__global__ __launch_bounds__(256) void gemm_k(GemmArgs g) {
  int z = blockIdx.z;
  int kp = z % g.kparts;
  int zz = z / g.kparts;
  int zi = zz / g.bdiv, zj = zz % g.bdiv;
  long aoff = (long)zi * g.sA1 + (long)zj * g.sA2;
  long boff = (long)zi * g.sB1 + (long)zj * g.sB2;
  long coff = (long)zi * g.sC1 + (long)zj * g.sC2;
  const float* Af = (const float*)g.A + aoff;
  const u16* Ah = (const u16*)g.A + aoff;
  const u16* Bh = (const u16*)g.B + boff;

  int m0 = blockIdx.y * 64, n0 = blockIdx.x * 64;
  __shared__ u16 As[64][LDK];
  __shared__ u16 Bs[64][LDK];
  int tid = threadIdx.x;
  int wave = tid >> 6, lane = tid & 63;
  int wr = (wave >> 1) * 32, wc = (wave & 1) * 32;
  int lr = lane & 15, qrow = lane >> 4;

  floatx4 acc[2][2];
#pragma unroll
  for (int i = 0; i < 2; ++i)
#pragma unroll
    for (int j = 0; j < 2; ++j)
#pragma unroll
      for (int r = 0; r < 4; ++r) acc[i][j][r] = 0.f;

  int r = tid >> 2, kc = (tid & 3) << 4;
  int kb0 = kp * g.Kc, kb1 = kb0 + g.Kc;
  for (int k0 = kb0; k0 < kb1; k0 += 64) {
    if (g.amode == 0) {
      const float* ap = Af + (long)(m0 + r) * g.lda + k0 + kc;
      float4 a0 = *(const float4*)ap, a1 = *(const float4*)(ap + 4);
      float4 a2 = *(const float4*)(ap + 8), a3 = *(const float4*)(ap + 12);
      union { u16 s[8]; uint4 v; } u0, u1;
      u0.s[0] = to_bf16(a0.x); u0.s[1] = to_bf16(a0.y); u0.s[2] = to_bf16(a0.z); u0.s[3] = to_bf16(a0.w);
      u0.s[4] = to_bf16(a1.x); u0.s[5] = to_bf16(a1.y); u0.s[6] = to_bf16(a1.z); u0.s[7] = to_bf16(a1.w);
      u1.s[0] = to_bf16(a2.x); u1.s[1] = to_bf16(a2.y); u1.s[2] = to_bf16(a2.z); u1.s[3] = to_bf16(a2.w);
      u1.s[4] = to_bf16(a3.x); u1.s[5] = to_bf16(a3.y); u1.s[6] = to_bf16(a3.z); u1.s[7] = to_bf16(a3.w);
      *(uint4*)&As[r][kc] = u0.v; *(uint4*)&As[r][kc + 8] = u1.v;
    } else {
      const u16* ap = Ah + (long)(m0 + r) * g.lda + k0 + kc;
      *(uint4*)&As[r][kc] = *(const uint4*)ap;
      *(uint4*)&As[r][kc + 8] = *(const uint4*)(ap + 8);
    }
    {
      const u16* bp = Bh + (long)(n0 + r) * g.ldb + k0 + kc;
      *(uint4*)&Bs[r][kc] = *(const uint4*)bp;
      *(uint4*)&Bs[r][kc + 8] = *(const uint4*)(bp + 8);
    }
    __syncthreads();
#pragma unroll
    for (int ks = 0; ks < 2; ++ks) {
      int kq = ks * 32 + qrow * 8;
      bf16x8 a0 = *(const bf16x8*)&As[wr + lr][kq];
      bf16x8 a1 = *(const bf16x8*)&As[wr + 16 + lr][kq];
      bf16x8 b0 = *(const bf16x8*)&Bs[wc + lr][kq];
      bf16x8 b1 = *(const bf16x8*)&Bs[wc + 16 + lr][kq];
      acc[0][0] = __builtin_amdgcn_mfma_f32_16x16x32_bf16(a0, b0, acc[0][0], 0, 0, 0);
      acc[0][1] = __builtin_amdgcn_mfma_f32_16x16x32_bf16(a0, b1, acc[0][1], 0, 0, 0);
      acc[1][0] = __builtin_amdgcn_mfma_f32_16x16x32_bf16(a1, b0, acc[1][0], 0, 0, 0);
      acc[1][1] = __builtin_amdgcn_mfma_f32_16x16x32_bf16(a1, b1, acc[1][1], 0, 0, 0);
    }
    __syncthreads();
  }

#pragma unroll
  for (int mt = 0; mt < 2; ++mt)
#pragma unroll
    for (int nt = 0; nt < 2; ++nt) {
      int row0 = m0 + wr + mt * 16 + qrow * 4;
      int col = n0 + wc + nt * 16 + lr;
      if (g.cmode == 2) {
        ushort4 o;
        o.x = to_bf16(acc[mt][nt][0] * g.alpha);
        o.y = to_bf16(acc[mt][nt][1] * g.alpha);
        o.z = to_bf16(acc[mt][nt][2] * g.alpha);
        o.w = to_bf16(acc[mt][nt][3] * g.alpha);
        *(ushort4*)((u16*)g.C + coff + (long)col * g.ldc + row0) = o;
      } else {
#pragma unroll
        for (int rr = 0; rr < 4; ++rr) {
          int row = row0 + rr;
          float v = acc[mt][nt][rr] * g.alpha;
          if (g.cmode == 3) {
            atomicAdd((float*)g.C + coff + (long)row * g.ldc + col, v);
          } else {
            if (g.bias) v += g.bias[col];
            if (g.res) v += g.res[(long)row * g.ldres + col];
            if (g.act) v = 0.5f * v * (1.0f + erff(v * 0.70710678118654752f));
            if (g.cmode == 1) ((u16*)g.C + coff)[(long)row * g.ldc + col] = to_bf16(v);
            else ((float*)g.C + coff)[(long)row * g.ldc + col] = v;
          }
        }
      }
    }
}

struct FAttnArgs {
  const u16* Q; const u16* K; const u16* V; const u16* QP;
  void* O;
  int L; long sKb, sVb; int ldV;
  float scale;
  int obf16;
};

// Fused flash attention. Block = (qtile, head h, sample b). D=64.
// Q bf16 [b*512+s][512] head slice at col h*64.
// K bf16: a.K + b*sKb + t*512 + h*64.   V^T bf16: a.V + b*sVb + (h*64+d)*ldV + t.
// QP (self only): bf16 [b][h][512][1152], includes *8; added at j=k+511-q (j<1152).
__global__ __launch_bounds__(256) void fattn_k(FAttnArgs a) {
  int qt = blockIdx.x, h = blockIdx.y, b = blockIdx.z;
  int tid = threadIdx.x, wave = tid >> 6, lane = tid & 63;
  int lr = lane & 15, quad = lane >> 4;
  __shared__ u16 Qs[64][LDK];
  __shared__ u16 Ks[64][LDK];
  __shared__ u16 Vs[64][LDK];
  __shared__ u16 Ps[4][16][LDK];
  int r = tid >> 2, c = (tid & 3) << 4;
  {
    const u16* qp = a.Q + (long)(b * 512 + qt * 64 + r) * 512 + h * 64 + c;
    *(uint4*)&Qs[r][c] = *(const uint4*)qp;
    *(uint4*)&Qs[r][c + 8] = *(const uint4*)(qp + 8);
  }
  const u16* qpp = a.QP ? a.QP + (long)b * 4718592 + (long)h * 589824 : nullptr;
  float m_run[4], l_run[4];
  floatx4 oacc[4];
#pragma unroll
  for (int i = 0; i < 4; ++i) {
    m_run[i] = -1e30f; l_run[i] = 0.f;
#pragma unroll
    for (int j = 0; j < 4; ++j) oacc[i][j] = 0.f;
  }

  for (int kt = 0; kt < a.L; kt += 64) {
    {
      const u16* kp = a.K + (long)b * a.sKb + (long)(kt + r) * 512 + h * 64 + c;
      *(uint4*)&Ks[r][c] = *(const uint4*)kp;
      *(uint4*)&Ks[r][c + 8] = *(const uint4*)(kp + 8);
      const u16* vp = a.V + (long)b * a.sVb + (long)(h * 64 + r) * a.ldV + kt + c;
      *(uint4*)&Vs[r][c] = *(const uint4*)vp;
      *(uint4*)&Vs[r][c + 8] = *(const uint4*)(vp + 8);
    }
    __syncthreads();
    floatx4 sacc[4];
#pragma unroll
    for (int nt = 0; nt < 4; ++nt)
#pragma unroll
      for (int j = 0; j < 4; ++j) sacc[nt][j] = 0.f;
#pragma unroll
    for (int ks = 0; ks < 2; ++ks) {
      int kq = ks * 32 + quad * 8;
      bf16x8 av = *(const bf16x8*)&Qs[wave * 16 + lr][kq];
#pragma unroll
      for (int nt = 0; nt < 4; ++nt) {
        bf16x8 bb = *(const bf16x8*)&Ks[nt * 16 + lr][kq];
        sacc[nt] = __builtin_amdgcn_mfma_f32_16x16x32_bf16(av, bb, sacc[nt], 0, 0, 0);
      }
    }
    // scores: s*scale + shifted QP
#pragma unroll
    for (int nt = 0; nt < 4; ++nt)
#pragma unroll
      for (int rr = 0; rr < 4; ++rr) {
        float v = sacc[nt][rr] * a.scale;
        if (qpp) {
          int row_l = wave * 16 + quad * 4 + rr;
          int j = kt + nt * 16 + lr + 511 - qt * 64 - row_l;
          if (j < 1152) v += bf2f(qpp[(long)(qt * 64 + row_l) * 1152 + j]);
        }
        sacc[nt][rr] = v;
      }
    // online softmax (row replicated across 16 lanes of a quad)
#pragma unroll
    for (int rr = 0; rr < 4; ++rr) {
      float m = -1e30f;
#pragma unroll
      for (int nt = 0; nt < 4; ++nt) m = fmaxf(m, sacc[nt][rr]);
      for (int o = 8; o > 0; o >>= 1) m = fmaxf(m, __shfl_xor(m, o, 64));
      float mn = fmaxf(m_run[rr], m);
      float al = __expf(m_run[rr] - mn);
      m_run[rr] = mn;
      float s = 0.f;
#pragma unroll
      for (int nt = 0; nt < 4; ++nt) {
        float p = __expf(sacc[nt][rr] - mn);
        sacc[nt][rr] = p;
        s += p;
      }
      for (int o = 8; o > 0; o >>= 1) s += __shfl_xor(s, o, 64);
      l_run[rr] = l_run[rr] * al + s;
#pragma unroll
      for (int nt = 0; nt < 4; ++nt) oacc[nt][rr] *= al;
    }
    // P (C-layout) -> LDS -> A-layout
#pragma unroll
    for (int nt = 0; nt < 4; ++nt) {
      Ps[wave][quad * 4 + 0][nt * 16 + lr] = to_bf16(sacc[nt][0]);
      Ps[wave][quad * 4 + 1][nt * 16 + lr] = to_bf16(sacc[nt][1]);
      Ps[wave][quad * 4 + 2][nt * 16 + lr] = to_bf16(sacc[nt][2]);
      Ps[wave][quad * 4 + 3][nt * 16 + lr] = to_bf16(sacc[nt][3]);
    }
#pragma unroll
    for (int ks = 0; ks < 2; ++ks) {
      int kq = ks * 32 + quad * 8;
      bf16x8 av = *(const bf16x8*)&Ps[wave][lr][kq];
#pragma unroll
      for (int nt = 0; nt < 4; ++nt) {
        bf16x8 bb = *(const bf16x8*)&Vs[nt * 16 + lr][kq];
        oacc[nt] = __builtin_amdgcn_mfma_f32_16x16x32_bf16(av, bb, oacc[nt], 0, 0, 0);
      }
    }
    __syncthreads();
  }
  float inv[4];
#pragma unroll
  for (int rr = 0; rr < 4; ++rr) inv[rr] = 1.f / l_run[rr];
#pragma unroll
  for (int nt = 0; nt < 4; ++nt)
#pragma unroll
    for (int rr = 0; rr < 4; ++rr) {
      long row = b * 512 + qt * 64 + wave * 16 + quad * 4 + rr;
      float v = oacc[nt][rr] * inv[rr];
      if (a.obf16) ((u16*)a.O)[row * 512 + h * 64 + nt * 16 + lr] = to_bf16(v);
      else ((float*)a.O)[row * 512 + h * 64 + nt * 16 + lr] = v;
    }
}

__global__ __launch_bounds__(256) void embed_k(const int* __restrict__ trg,
                                               const float* __restrict__ embed,
                                               float* __restrict__ x) {
  int i = blockIdx.x * 256 + threadIdx.x;
  int row = i >> 9, d = i & 511;
  x[i] = embed[(long)trg[row] * 512 + d];
}

__global__ __launch_bounds__(256) void concat_kv_k(const float* __restrict__ cmem,
                                                   const float* __restrict__ mem,
                                                   const float* __restrict__ x,
                                                   u16* __restrict__ kv) {
  long i = (long)blockIdx.x * 256 + threadIdx.x;  // 4*1152*512
  int d = i & 511;
  long t = (i >> 9) % 1152;
  long b = (i >> 9) / 1152;
  float v;
  if (t < 128) v = cmem[(b * 128 + t) * 512 + d];
  else if (t < 640) v = mem[(b * 512 + (t - 128)) * 512 + d];
  else v = x[(b * 512 + (t - 640)) * 512 + d];
  kv[i] = to_bf16(v);
}

__global__ __launch_bounds__(256) void layernorm_k(const float* __restrict__ X,
                                                   const float* __restrict__ g,
                                                   const float* __restrict__ b,
                                                   u16* __restrict__ Y) {
  long row = blockIdx.x;
  const float* x = X + row * 512;
  int tid = threadIdx.x;
  float v0 = x[tid], v1 = x[tid + 256];
  __shared__ float red[256];
  red[tid] = v0 + v1; __syncthreads();
  for (int o = 128; o > 0; o >>= 1) { if (tid < o) red[tid] += red[tid + o]; __syncthreads(); }
  float mu = red[0] * (1.f / 512.f);
  __syncthreads();
  float d0 = v0 - mu, d1 = v1 - mu;
  red[tid] = d0 * d0 + d1 * d1; __syncthreads();
  for (int o = 128; o > 0; o >>= 1) { if (tid < o) red[tid] += red[tid + o]; __syncthreads(); }
  float rstd = rsqrtf(red[0] * (1.f / 512.f) + 1e-5f);
  Y[row * 512 + tid] = to_bf16(d0 * rstd * g[tid] + b[tid]);
  Y[row * 512 + tid + 256] = to_bf16(d1 * rstd * g[tid + 256] + b[tid + 256]);
}

__global__ __launch_bounds__(256) void preset_k(float* __restrict__ C,
                                                const float* __restrict__ res,
                                                const float* __restrict__ bias, int nmask) {
  long i = (long)blockIdx.x * 256 + threadIdx.x;
  float v = 0.f;
  if (res) v += res[i];
  if (bias) v += bias[i & nmask];
  C[i] = v;
}

__global__ __launch_bounds__(256) void loss_k(const float* __restrict__ a,
                                              const float* __restrict__ b,
                                              float* __restrict__ acc) {
  float s = 0.f;
  for (long i = (long)blockIdx.x * 256 + threadIdx.x; i < 1048576; i += 256L * 128) {
    float d = a[i] - b[i]; s += d * d;
  }
  for (int o = 32; o > 0; o >>= 1) s += __shfl_xor(s, o, 64);
  __shared__ float red[4];
  if ((threadIdx.x & 63) == 0) red[threadIdx.x >> 6] = s;
  __syncthreads();
  if (threadIdx.x == 0) atomicAdd(acc, red[0] + red[1] + red[2] + red[3]);
}

__global__ __launch_bounds__(256) void transpose_bf16_k(const float* __restrict__ in,
                                                        u16* __restrict__ out, int K, int N) {
  long z = blockIdx.z;
  in += z * (long)K * N; out += z * (long)K * N;
  __shared__ float t[32][33];
  int n0 = blockIdx.x * 32, k0 = blockIdx.y * 32;
  int tx = threadIdx.x, ty = threadIdx.y;
  for (int j = 0; j < 32; j += 8) t[ty + j][tx] = in[(long)(k0 + ty + j) * N + n0 + tx];
  __syncthreads();
  for (int j = 0; j < 32; j += 8) out[(long)(n0 + ty + j) * K + k0 + tx] = to_bf16(t[tx][ty + j]);
}

__global__ __launch_bounds__(256) void convw_k(const float* __restrict__ in,
                                               u16* __restrict__ out) {
  int i = blockIdx.x * 256 + threadIdx.x;
  long z = blockIdx.z;
  int o = i >> 11, k = i & 2047;
  int r = k >> 9, d = k & 511;
  out[z * 1048576 + i] = to_bf16(in[z * 1048576 + o * 2048 + d * 4 + r]);
}

__global__ __launch_bounds__(256) void cvt_bf16_k(const float* __restrict__ in,
                                                  u16* __restrict__ out, int n) {
  int i = blockIdx.x * 256 + threadIdx.x;
  if (i < n) out[i] = to_bf16(in[i]);
}

__global__ __launch_bounds__(256) void finalize_k(const float* __restrict__ x,
                                                  const float* __restrict__ loss,
                                                  float* __restrict__ out) {
  long i = (long)blockIdx.x * 256 + threadIdx.x;
  if (i < 1048576) out[i] = x[i];
  else if (i == 1048576) out[i] = loss[0] * (1.f / (1048576.f * 4.f));
}

extern "C" void kernel_launch(void* const* d_in, const int* in_sizes, int n_in,
                              void* d_out, int out_size, void* d_ws, size_t ws_size,
                              hipStream_t stream) {
  (void)in_sizes; (void)n_in; (void)out_size;
  const int* trg = (const int*)d_in[0];
  const float* latent = (const float*)d_in[3];
  const float* mems = (const float*)d_in[4];
  const float* cmems = (const float*)d_in[5];
  const float* pos_emb = (const float*)d_in[6];
  const float* embed = (const float*)d_in[7];
  const float* W_self = (const float*)d_in[8];
  const float* ln1_g = (const float*)d_in[9];
  const float* ln1_b = (const float*)d_in[10];
  const float* conv_w = (const float*)d_in[11];
  const float* conv_b = (const float*)d_in[12];
  const float* W_src = (const float*)d_in[13];
  const float* ln2_g = (const float*)d_in[14];
  const float* ln2_b = (const float*)d_in[15];
  const float* w1 = (const float*)d_in[16];
  const float* b1 = (const float*)d_in[17];
  const float* w2 = (const float*)d_in[18];
  const float* b2 = (const float*)d_in[19];

  float* ws = (float*)d_ws;
  long off = 0;
  auto alloc = [&](long n) { float* p = ws + off; off += (n + 63) & ~63L; return p; };
  float* x    = alloc(1048576);
  float* t0   = alloc(1048576);
  float* t1   = alloc(1048576);
  float* ncm  = alloc(262144);
  float* ocm  = alloc(1048576);
  float* oold = alloc(1048576);
  u16* acat = (u16*)alloc(524288);    // [2048][512] bf16
  u16* h1   = (u16*)alloc(2097152);   // [2048][2048] bf16
  u16* qb   = (u16*)alloc(524288);
  u16* xa   = (u16*)alloc(524288);
  u16* t1h  = (u16*)alloc(524288);
  u16* kvcat= (u16*)alloc(1179648);   // [4][1152][512] bf16
  u16* kbuf = (u16*)alloc(1179648);   // self: [4][1152][512]; rattn: [2048][512]
  u16* vbuf = (u16*)alloc(1179648);   // self: [4][512][1152] V^T; rattn: [512][2048] V^T
  u16* kcm  = (u16*)alloc(131072);
  u16* vcm  = (u16*)alloc(131072);
  u16* klat = (u16*)alloc(262144);
  u16* vlat = (u16*)alloc(262144);
  u16* QPb  = (u16*)alloc(9437184);   // [4][8][512][1152] bf16, includes *8
  u16* wts  = (u16*)alloc(2097152);
  u16* wsr  = (u16*)alloc(2097152);
  u16* w1t  = (u16*)alloc(2097152);
  u16* w2t  = (u16*)alloc(2097152);
  u16* cwt  = (u16*)alloc(2097152);
  u16* post = (u16*)alloc(294912);    // [8][1152][64] bf16 (589824 u16 = 294912 floats)
  float* lossacc = alloc(64);
  if ((size_t)off * 4 > ws_size) return;

  hipMemsetAsync(lossacc, 0, 4, stream);
  embed_k<<<4096, 256, 0, stream>>>(trg, embed, x);
  transpose_bf16_k<<<dim3(16, 16, 16), dim3(32, 8), 0, stream>>>(W_self, wts, 512, 512);
  transpose_bf16_k<<<dim3(16, 16, 16), dim3(32, 8), 0, stream>>>(W_src, wsr, 512, 512);
  transpose_bf16_k<<<dim3(64, 16, 4), dim3(32, 8), 0, stream>>>(w1, w1t, 512, 2048);
  transpose_bf16_k<<<dim3(16, 64, 4), dim3(32, 8), 0, stream>>>(w2, w2t, 2048, 512);
  convw_k<<<dim3(4096, 1, 4), 256, 0, stream>>>(conv_w, cwt);
  cvt_bf16_k<<<2304, 256, 0, stream>>>(pos_emb, post, 589824);

  auto ga = []() { GemmArgs g; g.alpha = 1.f; g.bias = nullptr; g.res = nullptr; g.ldres = 512;
                   g.amode = 0; g.cmode = 0; g.act = 0; g.bdiv = 1; g.kparts = 1;
                   g.sA1 = g.sA2 = g.sB1 = g.sB2 = g.sC1 = g.sC2 = 0; g.N = 0; return g; };
  auto run = [&](GemmArgs& g, int gx, int gy, int gz) {
    gemm_k<<<dim3(gx, gy, gz), 256, 0, stream>>>(g);
  };
  auto fa = [&](const u16* Q, const u16* K, const u16* V, const u16* QP, void* O,
                int L, long sKb, long sVb, int ldV, float scale, int obf16) {
    FAttnArgs a; a.Q = Q; a.K = K; a.V = V; a.QP = QP; a.O = O;
    a.L = L; a.sKb = sKb; a.sVb = sVb; a.ldV = ldV; a.scale = scale; a.obf16 = obf16;
    fattn_k<<<dim3(8, 8, 4), 256, 0, stream>>>(a);
  };

  for (int l = 0; l < 4; ++l) {
    const u16* Wt0 = wts + (l * 4 + 0) * 262144;
    const u16* Wt1 = wts + (l * 4 + 1) * 262144;
    const u16* Wt2 = wts + (l * 4 + 2) * 262144;
    const u16* Wt3 = wts + (l * 4 + 3) * 262144;
    const u16* Ws0 = wsr + (l * 4 + 0) * 262144;
    const u16* Ws1 = wsr + (l * 4 + 1) * 262144;
    const u16* Ws2 = wsr + (l * 4 + 2) * 262144;
    const u16* Ws3 = wsr + (l * 4 + 3) * 262144;
    const float* mem_l = mems + (long)l * 1048576;
    const float* cmem_l = cmems + (long)l * 262144;

    // ===== self-attention =====
    concat_kv_k<<<9216, 256, 0, stream>>>(cmem_l, mem_l, x, kvcat);
    { GemmArgs g = ga(); g.A = x; g.lda = 512; g.B = Wt0; g.ldb = 512; g.C = qb; g.ldc = 512;
      g.cmode = 1; g.Kc = 512; run(g, 8, 32, 1); }
    { GemmArgs g = ga(); g.A = kvcat; g.amode = 1; g.lda = 512; g.B = Wt1; g.ldb = 512;
      g.C = kbuf; g.ldc = 512; g.cmode = 1; g.Kc = 512; run(g, 8, 72, 1); }
    { GemmArgs g = ga(); g.A = kvcat; g.amode = 1; g.lda = 512; g.sA1 = 589824; g.B = Wt2; g.ldb = 512;
      g.C = vbuf; g.ldc = 1152; g.sC1 = 589824; g.cmode = 2; g.Kc = 512; run(g, 8, 18, 4); }
    // QP[b][h][s][j] = 8*(q . pos[h][j]), bf16
    { GemmArgs g = ga(); g.A = qb; g.amode = 1; g.lda = 512; g.sA1 = 262144; g.sA2 = 64;
      g.B = post; g.ldb = 64; g.sB1 = 0; g.sB2 = 73728;
      g.C = QPb; g.ldc = 1152; g.sC1 = 4718592; g.sC2 = 589824;
      g.cmode = 1; g.alpha = 8.f; g.bdiv = 8; g.Kc = 64; run(g, 18, 8, 32); }
    fa(qb, kbuf, vbuf, QPb, acat, 1152, 589824, 589824, 1152, 0.125f, 1);
    { GemmArgs g = ga(); g.A = acat; g.amode = 1; g.lda = 512; g.B = Wt3; g.ldb = 512;
      g.C = t1; g.ldc = 512; g.res = x; g.Kc = 512; run(g, 8, 32, 1); }
    layernorm_k<<<2048, 256, 0, stream>>>(t1, ln1_g + l * 512, ln1_b + l * 512, xa);

    // ===== conv compress =====
    preset_k<<<1024, 256, 0, stream>>>(ncm, nullptr, conv_b + l * 512, 511);
    { GemmArgs g = ga(); g.A = mem_l; g.lda = 2048; g.B = cwt + (long)l * 1048576; g.ldb = 2048;
      g.C = ncm; g.ldc = 512; g.cmode = 3; g.kparts = 8; g.Kc = 256; run(g, 8, 8, 8); }

    // ===== rattn (compression loss) =====
    { GemmArgs g = ga(); g.A = xa; g.amode = 1; g.lda = 512; g.B = Wt0; g.ldb = 512;
      g.C = qb; g.ldc = 512; g.cmode = 1; g.Kc = 512; run(g, 8, 32, 1); }
    { GemmArgs g = ga(); g.A = ncm; g.lda = 512; g.B = Wt1; g.ldb = 512;
      g.C = kcm; g.ldc = 512; g.cmode = 1; g.Kc = 512; run(g, 8, 8, 1); }
    { GemmArgs g = ga(); g.A = ncm; g.lda = 512; g.B = Wt2; g.ldb = 512;
      g.C = vcm; g.ldc = 512; g.cmode = 2; g.Kc = 512; run(g, 8, 8, 1); }
    { GemmArgs g = ga(); g.A = mem_l; g.lda = 512; g.B = Wt1; g.ldb = 512;
      g.C = kbuf; g.ldc = 512; g.cmode = 1; g.Kc = 512; run(g, 8, 32, 1); }
    { GemmArgs g = ga(); g.A = mem_l; g.lda = 512; g.B = Wt2; g.ldb = 512;
      g.C = vbuf; g.ldc = 2048; g.cmode = 2; g.Kc = 512; run(g, 8, 32, 1); }
    fa(qb, kcm, vcm, nullptr, ocm, 128, 65536, 128, 512, 0.125f, 0);
    fa(qb, kbuf, vbuf, nullptr, oold, 512, 262144, 512, 2048, 0.125f, 0);
    loss_k<<<128, 256, 0, stream>>>(ocm, oold, lossacc);

    // ===== cross attention (256 latent keys) =====
    { GemmArgs g = ga(); g.A = xa; g.amode = 1; g.lda = 512; g.B = Ws0; g.ldb = 512;
      g.C = qb; g.ldc = 512; g.cmode = 1; g.Kc = 512; run(g, 8, 32, 1); }
    { GemmArgs g = ga(); g.A = latent; g.lda = 512; g.B = Ws1; g.ldb = 512;
      g.C = klat; g.ldc = 512; g.cmode = 1; g.Kc = 512; run(g, 8, 16, 1); }
    { GemmArgs g = ga(); g.A = latent; g.lda = 512; g.B = Ws2; g.ldb = 512;
      g.C = vlat; g.ldc = 1024; g.cmode = 2; g.Kc = 512; run(g, 8, 16, 1); }
    fa(qb, klat, vlat, nullptr, acat, 256, 131072, 256, 1024, 0.125f, 1);
    { GemmArgs g = ga(); g.A = acat; g.amode = 1; g.lda = 512; g.B = Ws3; g.ldb = 512;
      g.C = t0; g.ldc = 512; g.Kc = 512; run(g, 8, 32, 1); }
    layernorm_k<<<2048, 256, 0, stream>>>(t0, ln2_g + l * 512, ln2_b + l * 512, t1h);

    // ===== FF =====
    { GemmArgs g = ga(); g.A = t1h; g.amode = 1; g.lda = 512; g.B = w1t + (long)l * 1048576; g.ldb = 512;
      g.C = h1; g.ldc = 2048; g.cmode = 1; g.bias = b1 + l * 2048; g.act = 1; g.Kc = 512;
      run(g, 32, 32, 1); }
    preset_k<<<4096, 256, 0, stream>>>(x, t0, b2 + l * 512, 511);
    { GemmArgs g = ga(); g.A = h1; g.amode = 1; g.lda = 2048; g.B = w2t + (long)l * 1048576; g.ldb = 2048;
      g.C = x; g.ldc = 512; g.cmode = 3; g.kparts = 4; g.Kc = 512; run(g, 8, 32, 4); }
  }
  finalize_k<<<4097, 256, 0, stream>>>(x, lossacc, (float*)d_out);
}

// Round 8
// 1544.935 us; speedup vs baseline: 2.5013x; 1.1760x over previous
//
#include <hip/hip_runtime.h>
#include <math.h>

typedef float floatx4 __attribute__((ext_vector_type(4)));
typedef __bf16 bf16x8 __attribute__((ext_vector_type(8)));
typedef unsigned short u16;

#define LDK 72  // LDS row stride in ushorts (144B, 16B-aligned)

__device__ inline u16 to_bf16(float f) {
  union { float f; unsigned u; } v; v.f = f;
  unsigned u = v.u;
  u += 0x7FFFu + ((u >> 16) & 1u);
  return (u16)(u >> 16);
}
__device__ inline float bf2f(u16 h) {
  union { unsigned u; float f; } v; v.u = ((unsigned)h) << 16; return v.f;
}

struct GemmArgs {
  const void* A; const void* B; void* C;
  int lda, ldb, ldc, N, Kc;
  long sA1, sA2, sB1, sB2, sC1, sC2;
  float alpha;
  const float* bias;
  const float* res; int ldres;
  int amode;   // 0: A fp32, 1: A bf16
  int cmode;   // 0: fp32 C, 1: bf16 C, 2: bf16 C transposed, 3: fp32 atomicAdd
  int act;     // exact gelu
  int smode;   // shifted bf16 scatter: C[row][col+row-511] = bf16(v) if >=0
  int bdiv, kparts;
};

__global__ __launch_bounds__(256) void gemm_k(GemmArgs g) {
  int z = blockIdx.z;
  int kp = z % g.kparts;
  int zz = z / g.kparts;
  int zi = zz / g.bdiv, zj = zz % g.bdiv;
  long aoff = (long)zi * g.sA1 + (long)zj * g.sA2;
  long boff = (long)zi * g.sB1 + (long)zj * g.sB2;
  long coff = (long)zi * g.sC1 + (long)zj * g.sC2;
  const float* Af = (const float*)g.A + aoff;
  const u16* Ah = (const u16*)g.A + aoff;
  const u16* Bh = (const u16*)g.B + boff;

  int m0 = blockIdx.y * 64, n0 = blockIdx.x * 64;
  __shared__ u16 As[64][LDK];
  __shared__ u16 Bs[64][LDK];
  int tid = threadIdx.x;
  int wave = tid >> 6, lane = tid & 63;
  int wr = (wave >> 1) * 32, wc = (wave & 1) * 32;
  int lr = lane & 15, qrow = lane >> 4;

  floatx4 acc[2][2];
#pragma unroll
  for (int i = 0; i < 2; ++i)
#pragma unroll
    for (int j = 0; j < 2; ++j)
#pragma unroll
      for (int r = 0; r < 4; ++r) acc[i][j][r] = 0.f;

  int r = tid >> 2, kc = (tid & 3) << 4;
  int kb0 = kp * g.Kc, kb1 = kb0 + g.Kc;
  for (int k0 = kb0; k0 < kb1; k0 += 64) {
    if (g.amode == 0) {
      const float* ap = Af + (long)(m0 + r) * g.lda + k0 + kc;
      float4 a0 = *(const float4*)ap, a1 = *(const float4*)(ap + 4);
      float4 a2 = *(const float4*)(ap + 8), a3 = *(const float4*)(ap + 12);
      union { u16 s[8]; uint4 v; } u0, u1;
      u0.s[0] = to_bf16(a0.x); u0.s[1] = to_bf16(a0.y); u0.s[2] = to_bf16(a0.z); u0.s[3] = to_bf16(a0.w);
      u0.s[4] = to_bf16(a1.x); u0.s[5] = to_bf16(a1.y); u0.s[6] = to_bf16(a1.z); u0.s[7] = to_bf16(a1.w);
      u1.s[0] = to_bf16(a2.x); u1.s[1] = to_bf16(a2.y); u1.s[2] = to_bf16(a2.z); u1.s[3] = to_bf16(a2.w);
      u1.s[4] = to_bf16(a3.x); u1.s[5] = to_bf16(a3.y); u1.s[6] = to_bf16(a3.z); u1.s[7] = to_bf16(a3.w);
      *(uint4*)&As[r][kc] = u0.v; *(uint4*)&As[r][kc + 8] = u1.v;
    } else {
      const u16* ap = Ah + (long)(m0 + r) * g.lda + k0 + kc;
      *(uint4*)&As[r][kc] = *(const uint4*)ap;
      *(uint4*)&As[r][kc + 8] = *(const uint4*)(ap + 8);
    }
    {
      const u16* bp = Bh + (long)(n0 + r) * g.ldb + k0 + kc;
      *(uint4*)&Bs[r][kc] = *(const uint4*)bp;
      *(uint4*)&Bs[r][kc + 8] = *(const uint4*)(bp + 8);
    }
    __syncthreads();
#pragma unroll
    for (int ks = 0; ks < 2; ++ks) {
      int kq = ks * 32 + qrow * 8;
      bf16x8 a0 = *(const bf16x8*)&As[wr + lr][kq];
      bf16x8 a1 = *(const bf16x8*)&As[wr + 16 + lr][kq];
      bf16x8 b0 = *(const bf16x8*)&Bs[wc + lr][kq];
      bf16x8 b1 = *(const bf16x8*)&Bs[wc + 16 + lr][kq];
      acc[0][0] = __builtin_amdgcn_mfma_f32_16x16x32_bf16(a0, b0, acc[0][0], 0, 0, 0);
      acc[0][1] = __builtin_amdgcn_mfma_f32_16x16x32_bf16(a0, b1, acc[0][1], 0, 0, 0);
      acc[1][0] = __builtin_amdgcn_mfma_f32_16x16x32_bf16(a1, b0, acc[1][0], 0, 0, 0);
      acc[1][1] = __builtin_amdgcn_mfma_f32_16x16x32_bf16(a1, b1, acc[1][1], 0, 0, 0);
    }
    __syncthreads();
  }

#pragma unroll
  for (int mt = 0; mt < 2; ++mt)
#pragma unroll
    for (int nt = 0; nt < 2; ++nt) {
      int row0 = m0 + wr + mt * 16 + qrow * 4;
      int col = n0 + wc + nt * 16 + lr;
      if (g.cmode == 2) {
        ushort4 o;
        o.x = to_bf16(acc[mt][nt][0] * g.alpha);
        o.y = to_bf16(acc[mt][nt][1] * g.alpha);
        o.z = to_bf16(acc[mt][nt][2] * g.alpha);
        o.w = to_bf16(acc[mt][nt][3] * g.alpha);
        *(ushort4*)((u16*)g.C + coff + (long)col * g.ldc + row0) = o;
      } else {
#pragma unroll
        for (int rr = 0; rr < 4; ++rr) {
          int row = row0 + rr;
          float v = acc[mt][nt][rr] * g.alpha;
          if (g.cmode == 3) {
            atomicAdd((float*)g.C + coff + (long)row * g.ldc + col, v);
          } else if (g.smode) {
            int oc = col + row - 511;
            if (oc >= 0) ((u16*)g.C + coff)[(long)row * g.ldc + oc] = to_bf16(v);
          } else {
            if (g.bias) v += g.bias[col];
            if (g.res) v += g.res[(long)row * g.ldres + col];
            if (g.act) v = 0.5f * v * (1.0f + erff(v * 0.70710678118654752f));
            if (g.cmode == 1) ((u16*)g.C + coff)[(long)row * g.ldc + col] = to_bf16(v);
            else ((float*)g.C + coff)[(long)row * g.ldc + col] = v;
          }
        }
      }
    }
}

struct FAttnArgs {
  const u16* Q; const u16* K; const u16* V; const u16* QP;  // QP = pre-shifted SQP
  void* O; float* Opart; float* ml;
  int L, nsplit; long sKb, sVb; int ldV;
  float scale; int obf16;
};

// Fused flash attention, double-buffered K/V, optional pre-shifted pos bias,
// optional KV-split (unnormalized partials + m/l for a combine pass).
__global__ __launch_bounds__(256) void fattn_k(FAttnArgs a) {
  int qt = blockIdx.x, h = blockIdx.y;
  int b = blockIdx.z / a.nsplit, sp = blockIdx.z % a.nsplit;
  int Lc = a.L / a.nsplit, kt0 = sp * Lc, T = Lc >> 6;
  int tid = threadIdx.x, wave = tid >> 6, lane = tid & 63;
  int lr = lane & 15, quad = lane >> 4;
  __shared__ u16 Qs[64][LDK];
  __shared__ u16 Ks[2][64][LDK];
  __shared__ u16 Vs[2][64][LDK];
  __shared__ u16 Qp[4][16][LDK];
  __shared__ u16 Ps[4][16][LDK];
  int r = tid >> 2, c = (tid & 3) << 4;
  {
    const u16* qp = a.Q + (long)(b * 512 + qt * 64 + r) * 512 + h * 64 + c;
    *(uint4*)&Qs[r][c] = *(const uint4*)qp;
    *(uint4*)&Qs[r][c + 8] = *(const uint4*)(qp + 8);
  }
  const u16* Kb = a.K + (long)b * a.sKb + h * 64;
  const u16* Vb = a.V + (long)b * a.sVb + (long)(h * 64) * a.ldV;
  int qrow16 = lane >> 2, qc = (lane & 3) << 4;  // wave-private SQP tile loader
  const u16* QPr = a.QP ? a.QP + ((long)b * 8 + h) * 589824 +
                          (long)(qt * 64 + wave * 16 + qrow16) * 1152 : nullptr;
  // preload tile 0 straight into LDS buffer 0
  {
    const u16* kp = Kb + (long)(kt0 + r) * 512 + c;
    *(uint4*)&Ks[0][r][c] = *(const uint4*)kp;
    *(uint4*)&Ks[0][r][c + 8] = *(const uint4*)(kp + 8);
    const u16* vp = Vb + (long)r * a.ldV + kt0 + c;
    *(uint4*)&Vs[0][r][c] = *(const uint4*)vp;
    *(uint4*)&Vs[0][r][c + 8] = *(const uint4*)(vp + 8);
  }
  uint4 qpr0, qpr1;
  if (QPr) {  // 16 u16 per lane: two uint4s
    qpr0 = *(const uint4*)(QPr + kt0 + qc);
    qpr1 = *(const uint4*)(QPr + kt0 + qc + 8);
  }

  float m_run[4], l_run[4];
  floatx4 oacc[4];
#pragma unroll
  for (int i = 0; i < 4; ++i) {
    m_run[i] = -1e30f; l_run[i] = 0.f;
#pragma unroll
    for (int j = 0; j < 4; ++j) oacc[i][j] = 0.f;
  }

  for (int t = 0; t < T; ++t) {
    int cur = t & 1;
    bool more = (t + 1) < T;
    __syncthreads();
    // issue next-tile global loads AFTER the barrier (s_barrier drains vmcnt);
    // they overlap the whole compute phase below, waited at the LDS store.
    uint4 pk0, pk1, pv0, pv1;
    if (more) {
      int kt = kt0 + (t + 1) * 64;
      const u16* kp = Kb + (long)(kt + r) * 512 + c;
      pk0 = *(const uint4*)kp; pk1 = *(const uint4*)(kp + 8);
      const u16* vp = Vb + (long)r * a.ldV + kt + c;
      pv0 = *(const uint4*)vp; pv1 = *(const uint4*)(vp + 8);
    }
    floatx4 sacc[4];
#pragma unroll
    for (int nt = 0; nt < 4; ++nt)
#pragma unroll
      for (int j = 0; j < 4; ++j) sacc[nt][j] = 0.f;
#pragma unroll
    for (int ks = 0; ks < 2; ++ks) {
      int kq = ks * 32 + quad * 8;
      bf16x8 av = *(const bf16x8*)&Qs[wave * 16 + lr][kq];
#pragma unroll
      for (int nt = 0; nt < 4; ++nt) {
        bf16x8 bb = *(const bf16x8*)&Ks[cur][nt * 16 + lr][kq];
        sacc[nt] = __builtin_amdgcn_mfma_f32_16x16x32_bf16(av, bb, sacc[nt], 0, 0, 0);
      }
    }
    if (QPr) {
      // wave-private: store this tile's SQP regs, read per-element; no barrier needed
      *(uint4*)&Qp[wave][qrow16][qc] = qpr0;
      *(uint4*)&Qp[wave][qrow16][qc + 8] = qpr1;
#pragma unroll
      for (int nt = 0; nt < 4; ++nt)
#pragma unroll
        for (int rr = 0; rr < 4; ++rr)
          sacc[nt][rr] = sacc[nt][rr] * a.scale + bf2f(Qp[wave][quad * 4 + rr][nt * 16 + lr]);
      if (more) {
        qpr0 = *(const uint4*)(QPr + kt0 + (t + 1) * 64 + qc);
        qpr1 = *(const uint4*)(QPr + kt0 + (t + 1) * 64 + qc + 8);
      }
    } else {
#pragma unroll
      for (int nt = 0; nt < 4; ++nt)
#pragma unroll
        for (int rr = 0; rr < 4; ++rr) sacc[nt][rr] *= a.scale;
    }
    // online softmax (rows replicated across the 16 lanes of a quad)
#pragma unroll
    for (int rr = 0; rr < 4; ++rr) {
      float m = -1e30f;
#pragma unroll
      for (int nt = 0; nt < 4; ++nt) m = fmaxf(m, sacc[nt][rr]);
      for (int o = 8; o > 0; o >>= 1) m = fmaxf(m, __shfl_xor(m, o, 64));
      float mn = fmaxf(m_run[rr], m);
      float al = __expf(m_run[rr] - mn);
      m_run[rr] = mn;
      float s = 0.f;
#pragma unroll
      for (int nt = 0; nt < 4; ++nt) {
        float p = __expf(sacc[nt][rr] - mn);
        sacc[nt][rr] = p;
        s += p;
      }
      for (int o = 8; o > 0; o >>= 1) s += __shfl_xor(s, o, 64);
      l_run[rr] = l_run[rr] * al + s;
#pragma unroll
      for (int nt = 0; nt < 4; ++nt) oacc[nt][rr] *= al;
    }
    // P (C-layout) -> LDS -> A-layout (wave-private)
#pragma unroll
    for (int nt = 0; nt < 4; ++nt) {
      Ps[wave][quad * 4 + 0][nt * 16 + lr] = to_bf16(sacc[nt][0]);
      Ps[wave][quad * 4 + 1][nt * 16 + lr] = to_bf16(sacc[nt][1]);
      Ps[wave][quad * 4 + 2][nt * 16 + lr] = to_bf16(sacc[nt][2]);
      Ps[wave][quad * 4 + 3][nt * 16 + lr] = to_bf16(sacc[nt][3]);
    }
#pragma unroll
    for (int ks = 0; ks < 2; ++ks) {
      int kq = ks * 32 + quad * 8;
      bf16x8 av = *(const bf16x8*)&Ps[wave][lr][kq];
#pragma unroll
      for (int nt = 0; nt < 4; ++nt) {
        bf16x8 bb = *(const bf16x8*)&Vs[cur][nt * 16 + lr][kq];
        oacc[nt] = __builtin_amdgcn_mfma_f32_16x16x32_bf16(av, bb, oacc[nt], 0, 0, 0);
      }
    }
    if (more) {  // stage prefetched tile into the other buffer
      *(uint4*)&Ks[cur ^ 1][r][c] = pk0; *(uint4*)&Ks[cur ^ 1][r][c + 8] = pk1;
      *(uint4*)&Vs[cur ^ 1][r][c] = pv0; *(uint4*)&Vs[cur ^ 1][r][c + 8] = pv1;
    }
  }
  if (a.nsplit == 1) {
    float inv[4];
#pragma unroll
    for (int rr = 0; rr < 4; ++rr) inv[rr] = 1.f / l_run[rr];
#pragma unroll
    for (int nt = 0; nt < 4; ++nt)
#pragma unroll
      for (int rr = 0; rr < 4; ++rr) {
        long row = b * 512 + qt * 64 + wave * 16 + quad * 4 + rr;
        float v = oacc[nt][rr] * inv[rr];
        if (a.obf16) ((u16*)a.O)[row * 512 + h * 64 + nt * 16 + lr] = to_bf16(v);
        else ((float*)a.O)[row * 512 + h * 64 + nt * 16 + lr] = v;
      }
  } else {
#pragma unroll
    for (int nt = 0; nt < 4; ++nt)
#pragma unroll
      for (int rr = 0; rr < 4; ++rr) {
        long row = b * 512 + qt * 64 + wave * 16 + quad * 4 + rr;
        a.Opart[((long)sp * 2048 + row) * 512 + h * 64 + nt * 16 + lr] = oacc[nt][rr];
      }
    if (lr == 0)
#pragma unroll
      for (int rr = 0; rr < 4; ++rr) {
        long row = b * 512 + qt * 64 + wave * 16 + quad * 4 + rr;
        long mi = (((long)sp * 2048 + row) * 8 + h) * 2;
        a.ml[mi] = m_run[rr]; a.ml[mi + 1] = l_run[rr];
      }
  }
}

__global__ __launch_bounds__(256) void fcomb_k(const float* __restrict__ Opart,
                                               const float* __restrict__ ml,
                                               void* __restrict__ O, int nsplit, int obf16) {
  long i = (long)blockIdx.x * 256 + threadIdx.x;
  int row = (int)(i >> 9), col = (int)(i & 511), h = col >> 6;
  float m = -1e30f;
  for (int s = 0; s < nsplit; ++s)
    m = fmaxf(m, ml[(((long)s * 2048 + row) * 8 + h) * 2]);
  float l = 0.f, o = 0.f;
  for (int s = 0; s < nsplit; ++s) {
    long mi = (((long)s * 2048 + row) * 8 + h) * 2;
    float w = __expf(ml[mi] - m);
    l += w * ml[mi + 1];
    o += w * Opart[(long)s * 1048576 + i];
  }
  float v = o / l;
  if (obf16) ((u16*)O)[i] = to_bf16(v);
  else ((float*)O)[i] = v;
}

__global__ __launch_bounds__(256) void embed_k(const int* __restrict__ trg,
                                               const float* __restrict__ embed,
                                               float* __restrict__ x) {
  int i = blockIdx.x * 256 + threadIdx.x;
  int row = i >> 9, d = i & 511;
  x[i] = embed[(long)trg[row] * 512 + d];
}

__global__ __launch_bounds__(256) void concat_kv_k(const float* __restrict__ cmem,
                                                   const float* __restrict__ mem,
                                                   const float* __restrict__ x,
                                                   u16* __restrict__ kv) {
  long i = (long)blockIdx.x * 256 + threadIdx.x;
  int d = i & 511;
  long t = (i >> 9) % 1152;
  long b = (i >> 9) / 1152;
  float v;
  if (t < 128) v = cmem[(b * 128 + t) * 512 + d];
  else if (t < 640) v = mem[(b * 512 + (t - 128)) * 512 + d];
  else v = x[(b * 512 + (t - 640)) * 512 + d];
  kv[i] = to_bf16(v);
}

__global__ __launch_bounds__(256) void layernorm_k(const float* __restrict__ X,
                                                   const float* __restrict__ g,
                                                   const float* __restrict__ b,
                                                   u16* __restrict__ Y) {
  long row = blockIdx.x;
  const float* x = X + row * 512;
  int tid = threadIdx.x;
  float v0 = x[tid], v1 = x[tid + 256];
  __shared__ float red[256];
  red[tid] = v0 + v1; __syncthreads();
  for (int o = 128; o > 0; o >>= 1) { if (tid < o) red[tid] += red[tid + o]; __syncthreads(); }
  float mu = red[0] * (1.f / 512.f);
  __syncthreads();
  float d0 = v0 - mu, d1 = v1 - mu;
  red[tid] = d0 * d0 + d1 * d1; __syncthreads();
  for (int o = 128; o > 0; o >>= 1) { if (tid < o) red[tid] += red[tid + o]; __syncthreads(); }
  float rstd = rsqrtf(red[0] * (1.f / 512.f) + 1e-5f);
  Y[row * 512 + tid] = to_bf16(d0 * rstd * g[tid] + b[tid]);
  Y[row * 512 + tid + 256] = to_bf16(d1 * rstd * g[tid + 256] + b[tid + 256]);
}

__global__ __launch_bounds__(256) void preset_k(float* __restrict__ C,
                                                const float* __restrict__ res,
                                                const float* __restrict__ bias, int nmask) {
  long i = (long)blockIdx.x * 256 + threadIdx.x;
  float v = 0.f;
  if (res) v += res[i];
  if (bias) v += bias[i & nmask];
  C[i] = v;
}

__global__ __launch_bounds__(256) void loss_k(const float* __restrict__ a,
                                              const float* __restrict__ b,
                                              float* __restrict__ acc) {
  float s = 0.f;
  for (long i = (long)blockIdx.x * 256 + threadIdx.x; i < 1048576; i += 256L * 128) {
    float d = a[i] - b[i]; s += d * d;
  }
  for (int o = 32; o > 0; o >>= 1) s += __shfl_xor(s, o, 64);
  __shared__ float red[4];
  if ((threadIdx.x & 63) == 0) red[threadIdx.x >> 6] = s;
  __syncthreads();
  if (threadIdx.x == 0) atomicAdd(acc, red[0] + red[1] + red[2] + red[3]);
}

__global__ __launch_bounds__(256) void transpose_bf16_k(const float* __restrict__ in,
                                                        u16* __restrict__ out, int K, int N) {
  long z = blockIdx.z;
  in += z * (long)K * N; out += z * (long)K * N;
  __shared__ float t[32][33];
  int n0 = blockIdx.x * 32, k0 = blockIdx.y * 32;
  int tx = threadIdx.x, ty = threadIdx.y;
  for (int j = 0; j < 32; j += 8) t[ty + j][tx] = in[(long)(k0 + ty + j) * N + n0 + tx];
  __syncthreads();
  for (int j = 0; j < 32; j += 8) out[(long)(n0 + ty + j) * K + k0 + tx] = to_bf16(t[tx][ty + j]);
}

__global__ __launch_bounds__(256) void convw_k(const float* __restrict__ in,
                                               u16* __restrict__ out) {
  int i = blockIdx.x * 256 + threadIdx.x;
  long z = blockIdx.z;
  int o = i >> 11, k = i & 2047;
  int r = k >> 9, d = k & 511;
  out[z * 1048576 + i] = to_bf16(in[z * 1048576 + o * 2048 + d * 4 + r]);
}

__global__ __launch_bounds__(256) void cvt_bf16_k(const float* __restrict__ in,
                                                  u16* __restrict__ out, int n) {
  int i = blockIdx.x * 256 + threadIdx.x;
  if (i < n) out[i] = to_bf16(in[i]);
}

__global__ __launch_bounds__(256) void finalize_k(const float* __restrict__ x,
                                                  const float* __restrict__ loss,
                                                  float* __restrict__ out) {
  long i = (long)blockIdx.x * 256 + threadIdx.x;
  if (i < 1048576) out[i] = x[i];
  else if (i == 1048576) out[i] = loss[0] * (1.f / (1048576.f * 4.f));
}

extern "C" void kernel_launch(void* const* d_in, const int* in_sizes, int n_in,
                              void* d_out, int out_size, void* d_ws, size_t ws_size,
                              hipStream_t stream) {
  (void)in_sizes; (void)n_in; (void)out_size;
  const int* trg = (const int*)d_in[0];
  const float* latent = (const float*)d_in[3];
  const float* mems = (const float*)d_in[4];
  const float* cmems = (const float*)d_in[5];
  const float* pos_emb = (const float*)d_in[6];
  const float* embed = (const float*)d_in[7];
  const float* W_self = (const float*)d_in[8];
  const float* ln1_g = (const float*)d_in[9];
  const float* ln1_b = (const float*)d_in[10];
  const float* conv_w = (const float*)d_in[11];
  const float* conv_b = (const float*)d_in[12];
  const float* W_src = (const float*)d_in[13];
  const float* ln2_g = (const float*)d_in[14];
  const float* ln2_b = (const float*)d_in[15];
  const float* w1 = (const float*)d_in[16];
  const float* b1 = (const float*)d_in[17];
  const float* w2 = (const float*)d_in[18];
  const float* b2 = (const float*)d_in[19];

  float* ws = (float*)d_ws;
  long off = 0;
  auto alloc = [&](long n) { float* p = ws + off; off += (n + 63) & ~63L; return p; };
  float* x    = alloc(1048576);
  float* t0   = alloc(1048576);
  float* t1   = alloc(1048576);
  float* ncm  = alloc(262144);
  float* ocm  = alloc(1048576);
  float* oold = alloc(1048576);
  float* Opart= alloc(2097152);       // aliases h1 (disjoint liveness: attn vs FF)
  u16* h1   = (u16*)Opart;            // [2048][2048] bf16
  float* mlb  = alloc(65536);         // [2][2048][8][2]
  // [2048][512] bf16 buffers need 1048576 u16 = 524288 floats each
  // (R6/R7 FAILED with alloc(262144): qb/xa/t1h overlapped -> in-place gemm races)
  u16* acat = (u16*)alloc(524288);
  u16* qb   = (u16*)alloc(524288);
  u16* xa   = (u16*)alloc(524288);
  u16* t1h  = (u16*)alloc(524288);
  u16* kvcat= (u16*)alloc(1179648);
  u16* kbuf = (u16*)alloc(1179648);
  u16* vbuf = (u16*)alloc(1179648);
  u16* kcm  = (u16*)alloc(131072);
  u16* vcm  = (u16*)alloc(131072);
  u16* klat = (u16*)alloc(262144);
  u16* vlat = (u16*)alloc(262144);
  u16* SQP  = (u16*)alloc(9437184);   // [4][8][512][1152] bf16 pre-shifted, *8 folded
  u16* wts  = (u16*)alloc(2097152);
  u16* wsr  = (u16*)alloc(2097152);
  u16* w1t  = (u16*)alloc(2097152);
  u16* w2t  = (u16*)alloc(2097152);
  u16* cwt  = (u16*)alloc(2097152);
  u16* post = (u16*)alloc(294912);
  float* lossacc = alloc(64);
  if ((size_t)off * 4 > ws_size) return;

  hipMemsetAsync(lossacc, 0, 4, stream);
  hipMemsetAsync(SQP, 0, 37748736, stream);  // tail region (k>=641+q) is never scattered
  embed_k<<<4096, 256, 0, stream>>>(trg, embed, x);
  transpose_bf16_k<<<dim3(16, 16, 16), dim3(32, 8), 0, stream>>>(W_self, wts, 512, 512);
  transpose_bf16_k<<<dim3(16, 16, 16), dim3(32, 8), 0, stream>>>(W_src, wsr, 512, 512);
  transpose_bf16_k<<<dim3(64, 16, 4), dim3(32, 8), 0, stream>>>(w1, w1t, 512, 2048);
  transpose_bf16_k<<<dim3(16, 64, 4), dim3(32, 8), 0, stream>>>(w2, w2t, 2048, 512);
  convw_k<<<dim3(4096, 1, 4), 256, 0, stream>>>(conv_w, cwt);
  cvt_bf16_k<<<2304, 256, 0, stream>>>(pos_emb, post, 589824);

  auto ga = []() { GemmArgs g; g.alpha = 1.f; g.bias = nullptr; g.res = nullptr; g.ldres = 512;
                   g.amode = 0; g.cmode = 0; g.act = 0; g.smode = 0; g.bdiv = 1; g.kparts = 1;
                   g.sA1 = g.sA2 = g.sB1 = g.sB2 = g.sC1 = g.sC2 = 0; g.N = 0; return g; };
  auto run = [&](GemmArgs& g, int gx, int gy, int gz) {
    gemm_k<<<dim3(gx, gy, gz), 256, 0, stream>>>(g);
  };
  auto fa = [&](const u16* Q, const u16* K, const u16* V, const u16* QP, void* O,
                int L, int nsplit, long sKb, long sVb, int ldV, int obf16) {
    FAttnArgs a; a.Q = Q; a.K = K; a.V = V; a.QP = QP; a.O = O;
    a.Opart = Opart; a.ml = mlb;
    a.L = L; a.nsplit = nsplit; a.sKb = sKb; a.sVb = sVb; a.ldV = ldV;
    a.scale = 0.125f; a.obf16 = obf16;
    fattn_k<<<dim3(8, 8, 4 * nsplit), 256, 0, stream>>>(a);
    if (nsplit > 1) fcomb_k<<<4096, 256, 0, stream>>>(Opart, mlb, O, nsplit, obf16);
  };

  for (int l = 0; l < 4; ++l) {
    const u16* Wt0 = wts + (l * 4 + 0) * 262144;
    const u16* Wt1 = wts + (l * 4 + 1) * 262144;
    const u16* Wt2 = wts + (l * 4 + 2) * 262144;
    const u16* Wt3 = wts + (l * 4 + 3) * 262144;
    const u16* Ws0 = wsr + (l * 4 + 0) * 262144;
    const u16* Ws1 = wsr + (l * 4 + 1) * 262144;
    const u16* Ws2 = wsr + (l * 4 + 2) * 262144;
    const u16* Ws3 = wsr + (l * 4 + 3) * 262144;
    const float* mem_l = mems + (long)l * 1048576;
    const float* cmem_l = cmems + (long)l * 262144;

    // ===== self-attention =====
    concat_kv_k<<<9216, 256, 0, stream>>>(cmem_l, mem_l, x, kvcat);
    { GemmArgs g = ga(); g.A = x; g.lda = 512; g.B = Wt0; g.ldb = 512; g.C = qb; g.ldc = 512;
      g.cmode = 1; g.Kc = 512; run(g, 8, 32, 1); }
    { GemmArgs g = ga(); g.A = kvcat; g.amode = 1; g.lda = 512; g.B = Wt1; g.ldb = 512;
      g.C = kbuf; g.ldc = 512; g.cmode = 1; g.Kc = 512; run(g, 8, 72, 1); }
    { GemmArgs g = ga(); g.A = kvcat; g.amode = 1; g.lda = 512; g.sA1 = 589824; g.B = Wt2; g.ldb = 512;
      g.C = vbuf; g.ldc = 1152; g.sC1 = 589824; g.cmode = 2; g.Kc = 512; run(g, 8, 18, 4); }
    // SQP[b][h][q][k] = 8*(q . pos[h][k+511-q]) via shifted scatter epilogue, bf16
    { GemmArgs g = ga(); g.A = qb; g.amode = 1; g.lda = 512; g.sA1 = 262144; g.sA2 = 64;
      g.B = post; g.ldb = 64; g.sB1 = 0; g.sB2 = 73728;
      g.C = SQP; g.ldc = 1152; g.sC1 = 4718592; g.sC2 = 589824;
      g.smode = 1; g.alpha = 8.f; g.bdiv = 8; g.Kc = 64; run(g, 18, 8, 32); }
    fa(qb, kbuf, vbuf, SQP, acat, 1152, 2, 589824, 589824, 1152, 1);
    { GemmArgs g = ga(); g.A = acat; g.amode = 1; g.lda = 512; g.B = Wt3; g.ldb = 512;
      g.C = t1; g.ldc = 512; g.res = x; g.Kc = 512; run(g, 8, 32, 1); }
    layernorm_k<<<2048, 256, 0, stream>>>(t1, ln1_g + l * 512, ln1_b + l * 512, xa);

    // ===== conv compress =====
    preset_k<<<1024, 256, 0, stream>>>(ncm, nullptr, conv_b + l * 512, 511);
    { GemmArgs g = ga(); g.A = mem_l; g.lda = 2048; g.B = cwt + (long)l * 1048576; g.ldb = 2048;
      g.C = ncm; g.ldc = 512; g.cmode = 3; g.kparts = 8; g.Kc = 256; run(g, 8, 8, 8); }

    // ===== rattn (compression loss) =====
    { GemmArgs g = ga(); g.A = xa; g.amode = 1; g.lda = 512; g.B = Wt0; g.ldb = 512;
      g.C = qb; g.ldc = 512; g.cmode = 1; g.Kc = 512; run(g, 8, 32, 1); }
    { GemmArgs g = ga(); g.A = ncm; g.lda = 512; g.B = Wt1; g.ldb = 512;
      g.C = kcm; g.ldc = 512; g.cmode = 1; g.Kc = 512; run(g, 8, 8, 1); }
    { GemmArgs g = ga(); g.A = ncm; g.lda = 512; g.B = Wt2; g.ldb = 512;
      g.C = vcm; g.ldc = 512; g.cmode = 2; g.Kc = 512; run(g, 8, 8, 1); }
    { GemmArgs g = ga(); g.A = mem_l; g.lda = 512; g.B = Wt1; g.ldb = 512;
      g.C = kbuf; g.ldc = 512; g.cmode = 1; g.Kc = 512; run(g, 8, 32, 1); }
    { GemmArgs g = ga(); g.A = mem_l; g.lda = 512; g.B = Wt2; g.ldb = 512;
      g.C = vbuf; g.ldc = 2048; g.cmode = 2; g.Kc = 512; run(g, 8, 32, 1); }
    fa(qb, kcm, vcm, nullptr, ocm, 128, 1, 65536, 128, 512, 0);
    fa(qb, kbuf, vbuf, nullptr, oold, 512, 2, 262144, 512, 2048, 0);
    loss_k<<<128, 256, 0, stream>>>(ocm, oold, lossacc);

    // ===== cross attention (256 latent keys) =====
    { GemmArgs g = ga(); g.A = xa; g.amode = 1; g.lda = 512; g.B = Ws0; g.ldb = 512;
      g.C = qb; g.ldc = 512; g.cmode = 1; g.Kc = 512; run(g, 8, 32, 1); }
    { GemmArgs g = ga(); g.A = latent; g.lda = 512; g.B = Ws1; g.ldb = 512;
      g.C = klat; g.ldc = 512; g.cmode = 1; g.Kc = 512; run(g, 8, 16, 1); }
    { GemmArgs g = ga(); g.A = latent; g.lda = 512; g.B = Ws2; g.ldb = 512;
      g.C = vlat; g.ldc = 1024; g.cmode = 2; g.Kc = 512; run(g, 8, 16, 1); }
    fa(qb, klat, vlat, nullptr, acat, 256, 2, 131072, 256, 1024, 1);
    { GemmArgs g = ga(); g.A = acat; g.amode = 1; g.lda = 512; g.B = Ws3; g.ldb = 512;
      g.C = t0; g.ldc = 512; g.Kc = 512; run(g, 8, 32, 1); }
    layernorm_k<<<2048, 256, 0, stream>>>(t0, ln2_g + l * 512, ln2_b + l * 512, t1h);

    // ===== FF =====
    { GemmArgs g = ga(); g.A = t1h; g.amode = 1; g.lda = 512; g.B = w1t + (long)l * 1048576; g.ldb = 512;
      g.C = h1; g.ldc = 2048; g.cmode = 1; g.bias = b1 + l * 2048; g.act = 1; g.Kc = 512;
      run(g, 32, 32, 1); }
    preset_k<<<4096, 256, 0, stream>>>(x, t0, b2 + l * 512, 511);
    { GemmArgs g = ga(); g.A = h1; g.amode = 1; g.lda = 2048; g.B = w2t + (long)l * 1048576; g.ldb = 2048;
      g.C = x; g.ldc = 512; g.cmode = 3; g.kparts = 4; g.Kc = 512; run(g, 8, 32, 4); }
  }
  finalize_k<<<4097, 256, 0, stream>>>(x, lossacc, (float*)d_out);
}